// Round 15
// baseline (111.302 us; speedup 1.0000x reference)
//
#include <hip/hip_runtime.h>
#include <hip/hip_bf16.h>
#include <cstdint>

// ---------------------------------------------------------------------------
// Fused causal self-attention block (B=2, T=2048, C=1024, H=16, Dh=64), fp32 in/out.
// cvt fp32->bf16 -> QKV GEMM (Q pre-scaled, V written transposed) -> flash attn -> out GEMM.
// Workspace (48MB):
//   yb    @ 0     8 MB   bf16 x (xb) -> DEAD after gemm1 -> reused as yb
//   wqkvb @ 8 MB  6 MB   bf16 w_qkv [3072][1024]
//   wob   @ 14MB  2 MB   bf16 w_out [1024][1024]
//   qkvb  @ 16MB 24 MB   bf16 qkv [4096][3072] (Q scaled | K | V-region unused)
//   vt    @ 40MB  8 MB   bf16 Vt [32 bh][64 d][2048 t] (written by gemm1 epilogue)
// ---------------------------------------------------------------------------

typedef __bf16 bf16x8 __attribute__((ext_vector_type(8)));
typedef float  f32x4  __attribute__((ext_vector_type(4)));
typedef unsigned short u16x4 __attribute__((ext_vector_type(4)));
typedef unsigned int   u32x4 __attribute__((ext_vector_type(4)));

#define EMB   1024
#define HEADS 16
#define HD    64
#define TT    2048
#define NROWS 4096
#define QKVN  3072
#define SCL   0.18033688f   /* 0.125 * log2(e): folded into Q at gemm1 epilogue */
#define THR   11.0f         /* defer-max threshold, log2 units */

// ---- fused fp32 -> bf16 (8 elems / thread, 3 arrays in one launch) ----
__global__ void cvt_all(const float* __restrict__ x, const float* __restrict__ wq,
                        const float* __restrict__ wo, __bf16* __restrict__ xb,
                        __bf16* __restrict__ wqb, __bf16* __restrict__ wob) {
  const int bid = blockIdx.x;
  const float* in; __bf16* out; int i;
  if (bid < 2048)      { in = x;  out = xb;  i = bid * 256 + threadIdx.x; }
  else if (bid < 3584) { in = wq; out = wqb; i = (bid - 2048) * 256 + threadIdx.x; }
  else                 { in = wo; out = wob; i = (bid - 3584) * 256 + threadIdx.x; }
  const float4* p = (const float4*)in + (size_t)i * 2;
  float4 a = p[0], b = p[1];
  bf16x8 o;
  o[0] = (__bf16)a.x; o[1] = (__bf16)a.y; o[2] = (__bf16)a.z; o[3] = (__bf16)a.w;
  o[4] = (__bf16)b.x; o[5] = (__bf16)b.y; o[6] = (__bf16)b.z; o[7] = (__bf16)b.w;
  *((bf16x8*)out + i) = o;
}

__device__ __forceinline__ void gload_lds16(const void* g, void* l) {
  __builtin_amdgcn_global_load_lds(
      (const __attribute__((address_space(1))) void*)(uintptr_t)g,
      (__attribute__((address_space(3))) void*)(uint32_t)(uintptr_t)l,
      16, 0, 0);
}

// ---------------------------------------------------------------------------
// GEMM (R12): 128x128 tile, BK=64, chunk-swizzled staging, XCD swizzle.
// MODE 1 epilogue: Q scaled, K plain, V transposed to vt.
// ---------------------------------------------------------------------------
template <int MODE>
__global__ __launch_bounds__(256, 2)
void gemm_bt(const __bf16* __restrict__ A, const __bf16* __restrict__ Bm,
             void* __restrict__ Cout, __bf16* __restrict__ vt,
             int M, int N, int K) {
  __shared__ __align__(16) char As[128 * 128];
  __shared__ __align__(16) char Bs[128 * 128];
  const int tid  = threadIdx.x;
  const int lane = tid & 63;
  const int wid  = tid >> 6;
  const int wr = wid >> 1, wc = wid & 1;
  const int nwg = gridDim.x * gridDim.y;
  int flat = blockIdx.y * gridDim.x + blockIdx.x;
  flat = (flat & 7) * (nwg >> 3) + (flat >> 3);
  const int brow = (flat / gridDim.x) * 128;
  const int bcol = (flat % gridDim.x) * 128;
  const int fr = lane & 15, g = lane >> 4;

  f32x4 acc[4][4];
#pragma unroll
  for (int m = 0; m < 4; m++)
#pragma unroll
    for (int n = 0; n < 4; n++)
#pragma unroll
      for (int r = 0; r < 4; r++) acc[m][n][r] = 0.0f;

  for (int k0 = 0; k0 < K; k0 += 64) {
    __syncthreads();
#pragma unroll
    for (int i = 0; i < 4; i++) {
      const int c = tid + i * 256;
      const int row = c >> 3, pos = c & 7;
      const int sc = pos ^ (row & 7);
      gload_lds16(A  + (size_t)(brow + row) * K + k0 + sc * 8, As + c * 16);
      gload_lds16(Bm + (size_t)(bcol + row) * K + k0 + sc * 8, Bs + c * 16);
    }
    __syncthreads();

    bf16x8 af[4][2], bfr[4][2];
#pragma unroll
    for (int m = 0; m < 4; m++)
#pragma unroll
      for (int kc = 0; kc < 2; kc++) {
        const int row = wr * 64 + m * 16 + fr;
        af[m][kc] = *(const bf16x8*)(As + row * 128 + (((kc << 2) | g) ^ (fr & 7)) * 16);
      }
#pragma unroll
    for (int n = 0; n < 4; n++)
#pragma unroll
      for (int kc = 0; kc < 2; kc++) {
        const int row = wc * 64 + n * 16 + fr;
        bfr[n][kc] = *(const bf16x8*)(Bs + row * 128 + (((kc << 2) | g) ^ (fr & 7)) * 16);
      }
#pragma unroll
    for (int kc = 0; kc < 2; kc++)
#pragma unroll
      for (int m = 0; m < 4; m++)
#pragma unroll
        for (int n = 0; n < 4; n++)
          acc[m][n] = __builtin_amdgcn_mfma_f32_16x16x32_bf16(af[m][kc], bfr[n][kc], acc[m][n], 0, 0, 0);
  }

  const int rbase = brow + wr * 64 + g * 4;
  const int cbase = bcol + wc * 64 + fr;
  if (MODE == 0) {
#pragma unroll
    for (int m = 0; m < 4; m++)
#pragma unroll
      for (int n = 0; n < 4; n++) {
        const int col = cbase + n * 16;
#pragma unroll
        for (int r = 0; r < 4; r++)
          ((float*)Cout)[(size_t)(rbase + m * 16 + r) * N + col] = acc[m][n][r];
      }
  } else if (bcol < 2 * EMB) {
    const float qscale = (bcol < EMB) ? SCL : 1.0f;
#pragma unroll
    for (int m = 0; m < 4; m++)
#pragma unroll
      for (int n = 0; n < 4; n++) {
        const int col = cbase + n * 16;
#pragma unroll
        for (int r = 0; r < 4; r++)
          ((__bf16*)Cout)[(size_t)(rbase + m * 16 + r) * N + col] = (__bf16)(acc[m][n][r] * qscale);
      }
  } else {
#pragma unroll
    for (int m = 0; m < 4; m++) {
      const int row0 = rbase + m * 16;
      const int b = row0 >> 11, t0 = row0 & 2047;
#pragma unroll
      for (int n = 0; n < 4; n++) {
        const int vcol = cbase + n * 16 - 2 * EMB;
        const int bh = b * HEADS + (vcol >> 6);
        const int d  = vcol & 63;
        u16x4 pk;
#pragma unroll
        for (int r = 0; r < 4; r++) {
          const __bf16 h = (__bf16)acc[m][n][r];
          pk[r] = *(const unsigned short*)&h;
        }
        *(u16x4*)(vt + ((size_t)bh * HD + d) * TT + t0) = pk;
      }
    }
  }
}

// ---------------------------------------------------------------------------
// Causal flash attention v15 = v9 staging/pipeline + SWAPPED QK^T in-register
// softmax (T12).  S^T = mfma(K,Q): lane fr owns q-row q0+fr, regs hold
// kv = n*16 + g*4 + r.  Softmax fully in-register (15 in-lane max + 2 shfl,
// scalar m/l per lane, scalar rescale).  P never touches LDS: packed bf16
// pairs pk[n][w2] are routed to PV's B-operand (k = g*8+j) via 16 ds_bpermute
// + 8 cndmask per tile.  PV: O^T = mfma(A=Vt frag, B=P^T) - vb reads
// unchanged.  Removes per wave-tile: 16 ds_write_b16 + 2 ds_read_b128 +
// 2 ones-MFMA + 14 shfl.  Epilogue transposes O^T once via dead Kbuf.
// 4-deep K/V buffers, counted vmcnt(4); grid 1024 (32 chunks x 32 bh), LPT.
// LDS 64KB -> 2 blocks/CU.
// ---------------------------------------------------------------------------
__device__ __forceinline__ int psw(int row) {
  return (((row & 7) ^ ((row >> 3) & 7))) << 4;
}

__device__ __forceinline__ unsigned int pack_bf16(float a, float b) {
  const __bf16 ha = (__bf16)a, hb = (__bf16)b;
  const unsigned short ua = *(const unsigned short*)&ha;
  const unsigned short ub = *(const unsigned short*)&hb;
  return (unsigned int)ua | ((unsigned int)ub << 16);
}

__global__ __launch_bounds__(256, 2)
void attn_causal15(const __bf16* __restrict__ qkv, const __bf16* __restrict__ vt,
                   __bf16* __restrict__ yb) {
  __shared__ __align__(16) char Kbuf[4][8192];   // K[kv][d], chunk-swizzled
  __shared__ __align__(16) char Vbuf[4][8192];   // Vt[d][kv], chunk-swizzled

  const int tid = threadIdx.x;
  const int lane = tid & 63, w = tid >> 6;
  const int L = blockIdx.x;
  const int bh = L & 31;
  const int chunk = 31 - (L >> 5);               // LPT: longest first
  const int b = bh >> 4, h = bh & 15;
  const size_t rowbase = (size_t)b * TT;
  const int q0 = chunk * 64 + w * 16;
  const int fr = lane & 15, g = lane >> 4;
  const int ntiles = chunk + 1;

  bf16x8 qf[2];
#pragma unroll
  for (int kc = 0; kc < 2; kc++)
    qf[kc] = *(const bf16x8*)(qkv + (rowbase + q0 + fr) * QKVN + h * HD + kc * 32 + g * 8);

  f32x4 o[4];            // O^T frags: lane q=q0+fr holds d = n*16 + g*4 + r
  float lacc = 0.0f;     // row sum (scalar per lane)
  float ml = -1e30f;     // running max (scalar per lane)
#pragma unroll
  for (int n = 0; n < 4; n++)
#pragma unroll
    for (int r = 0; r < 4; r++) o[n][r] = 0.0f;

  auto stageKV = [&](int kt, int buf) {
#pragma unroll
    for (int i = 0; i < 2; i++) {
      const int c = tid + i * 256;
      const int row = c >> 3;
      const int c16 = (c & 7) ^ (row & 7);
      gload_lds16(qkv + (rowbase + kt * 64 + row) * QKVN + EMB + h * HD + c16 * 8,
                  Kbuf[buf] + c * 16);
    }
#pragma unroll
    for (int i = 0; i < 2; i++) {
      const int c = tid + i * 256;
      const int row = c >> 3;
      const int c16 = (c & 7) ^ (row & 7);
      gload_lds16(vt + ((size_t)bh * HD + row) * TT + kt * 64 + c16 * 8,
                  Vbuf[buf] + c * 16);
    }
  };

  // S^T = mfma(A=K, B=Q): s[n][r] = S[q=q0+fr][kv = kt*64 + n*16 + g*4 + r]
  auto doQK = [&](int kt, f32x4 (&s)[4]) {
    const char* Kc = Kbuf[kt & 3];
    bf16x8 kf[4][2];
#pragma unroll
    for (int n = 0; n < 4; n++)
#pragma unroll
      for (int kc = 0; kc < 2; kc++) {
        const int row = n * 16 + fr;
        kf[n][kc] = *(const bf16x8*)(Kc + row * 128 + (((kc << 2) | g) ^ (row & 7)) * 16);
      }
    __builtin_amdgcn_s_setprio(1);
#pragma unroll
    for (int n = 0; n < 4; n++) {
#pragma unroll
      for (int r = 0; r < 4; r++) s[n][r] = 0.0f;
#pragma unroll
      for (int kc = 0; kc < 2; kc++)
        s[n] = __builtin_amdgcn_mfma_f32_16x16x32_bf16(kf[n][kc], qf[kc], s[n], 0, 0, 0);
    }
    __builtin_amdgcn_s_setprio(0);
  };

  // in-register softmax + P^T B-operand assembly (pb[kc], k = g*8+j)
  auto doSM = [&](int kt, f32x4 (&s)[4], bf16x8 (&pb)[2]) {
    const int kv0 = kt * 64;
    if (kt == chunk) {                           // causal mask, diagonal tile
      const int qg = q0 + fr;
#pragma unroll
      for (int n = 0; n < 4; n++)
#pragma unroll
        for (int r = 0; r < 4; r++) {
          const int kg = kv0 + n * 16 + g * 4 + r;
          if (kg > qg) s[n][r] = -1e30f;
        }
    }
    // per-lane max over 16 values, then across the 4 g-groups
    float pm = s[0][0];
#pragma unroll
    for (int n = 0; n < 4; n++)
#pragma unroll
      for (int r = 0; r < 4; r++) pm = fmaxf(pm, s[n][r]);
    pm = fmaxf(pm, __shfl_xor(pm, 16, 64));
    pm = fmaxf(pm, __shfl_xor(pm, 32, 64));
    if (!__all(pm <= ml + THR)) {
      const float nm = fmaxf(ml, pm);
      const float f = __builtin_amdgcn_exp2f(ml - nm);
      ml = nm;
      lacc *= f;
#pragma unroll
      for (int n = 0; n < 4; n++)
#pragma unroll
        for (int r = 0; r < 4; r++) o[n][r] *= f;
    }
    float p[4][4];
    float ts = 0.0f;
#pragma unroll
    for (int n = 0; n < 4; n++)
#pragma unroll
      for (int r = 0; r < 4; r++) {
        p[n][r] = __builtin_amdgcn_exp2f(s[n][r] - ml);
        ts += p[n][r];
      }
    ts += __shfl_xor(ts, 16, 64);
    ts += __shfl_xor(ts, 32, 64);
    lacc += ts;
    // pack pairs: pk[n][w2] = bf16(p[n][2w2]) | bf16(p[n][2w2+1])<<16
    unsigned int pk[4][2];
#pragma unroll
    for (int n = 0; n < 4; n++)
#pragma unroll
      for (int w2 = 0; w2 < 2; w2++)
        pk[n][w2] = pack_bf16(p[n][2 * w2], p[n][2 * w2 + 1]);
    // route to B-frag: lane (fr,g) word w needs kv32 = g*8+2w(+1):
    //   src lane = fr + 16*((g&1)*2 + (w>>1)), src reg = pk[kc*2 + (g>=2)][w&1]
    const int sl0 = fr + 16 * ((g & 1) * 2);     // for w = 0,1
    const int sl1 = sl0 + 16;                    // for w = 2,3
#pragma unroll
    for (int kc = 0; kc < 2; kc++) {
      u32x4 bw;
#pragma unroll
      for (int ww = 0; ww < 4; ww++) {
        const int src = (ww < 2) ? sl0 : sl1;
        const unsigned int lo = (unsigned int)__shfl((int)pk[kc * 2][ww & 1], src, 64);
        const unsigned int hi = (unsigned int)__shfl((int)pk[kc * 2 + 1][ww & 1], src, 64);
        bw[ww] = (g & 2) ? hi : lo;
      }
      pb[kc] = *(bf16x8*)&bw;
    }
  };

  // O^T += mfma(A=Vt frag, B=P^T)
  auto doPV = [&](int kt, bf16x8 (&pb)[2]) {
    const char* Vc = Vbuf[kt & 3];
    bf16x8 vb[4][2];
#pragma unroll
    for (int n = 0; n < 4; n++)
#pragma unroll
      for (int kc = 0; kc < 2; kc++) {
        const int row = n * 16 + fr;
        vb[n][kc] = *(const bf16x8*)(Vc + row * 128 + (((kc << 2) | g) ^ (row & 7)) * 16);
      }
    __builtin_amdgcn_s_setprio(1);
#pragma unroll
    for (int kc = 0; kc < 2; kc++)
#pragma unroll
      for (int n = 0; n < 4; n++)
        o[n] = __builtin_amdgcn_mfma_f32_16x16x32_bf16(vb[n][kc], pb[kc], o[n], 0, 0, 0);
    __builtin_amdgcn_s_setprio(0);
  };

  // ---- prologue: fill pipeline (tiles 0..2), force 0,1 landed ----
  stageKV(0, 0);
  if (ntiles > 1) stageKV(1, 1);
  if (ntiles > 2) stageKV(2, 2);
  if (ntiles > 2) asm volatile("s_waitcnt vmcnt(4)" ::: "memory");
  else            asm volatile("s_waitcnt vmcnt(0)" ::: "memory");
  __builtin_amdgcn_s_barrier();

  bf16x8 pb[2];
  {                                   // tile 0: QK + softmax (pb ready)
    f32x4 s0[4];
    doQK(0, s0);
    doSM(0, s0, pb);
  }

  for (int t = 0; t < ntiles; t++) {
    if (t + 3 < ntiles) stageKV(t + 3, (t + 3) & 3);

    const bool nxt = (t + 1 < ntiles);
    f32x4 s[4];
    if (nxt) doQK(t + 1, s);          // overlaps PV(t)
    doPV(t, pb);                      // consumes pb(t)
    if (nxt) doSM(t + 1, s, pb);      // rescale o AFTER PV(t); makes pb(t+1)

    if (t + 3 < ntiles) asm volatile("s_waitcnt vmcnt(4)" ::: "memory");
    else                asm volatile("s_waitcnt vmcnt(0)" ::: "memory");
    __builtin_amdgcn_s_barrier();
  }

  // ---- epilogue: O^T -> [q][d] via per-wave LDS region (Kbuf dead) ----
  {
    char* Tw = (char*)Kbuf + w * 2048;           // [16 q][64 d] bf16, psw-swizzled
    const float inv = __builtin_amdgcn_rcpf(lacc);
#pragma unroll
    for (int n = 0; n < 4; n++)
#pragma unroll
      for (int r = 0; r < 4; r++) {
        const int d = n * 16 + g * 4 + r;
        *(__bf16*)(Tw + fr * 128 + ((d * 2) ^ psw(fr))) = (__bf16)(o[n][r] * inv);
      }
#pragma unroll
    for (int i = 0; i < 2; i++) {
      const int c = lane + i * 64;               // 128 16B-chunks
      const int row = c >> 3, pos = c & 7;
      const bf16x8 v = *(const bf16x8*)(Tw + row * 128 + ((pos * 16) ^ psw(row)));
      *(bf16x8*)(yb + (rowbase + q0 + row) * EMB + h * HD + pos * 8) = v;
    }
  }
}

extern "C" void kernel_launch(void* const* d_in, const int* in_sizes, int n_in,
                              void* d_out, int out_size, void* d_ws, size_t ws_size,
                              hipStream_t stream) {
  const float* x     = (const float*)d_in[0];
  const float* w_qkv = (const float*)d_in[1];
  const float* w_out = (const float*)d_in[2];
  float* out = (float*)d_out;

  char* ws = (char*)d_ws;
  __bf16* xb    = (__bf16*)(ws);                 // dead after gemm1 -> reused as yb
  __bf16* wqkvb = (__bf16*)(ws + (8ull  << 20));
  __bf16* wob   = (__bf16*)(ws + (14ull << 20));
  __bf16* qkvb  = (__bf16*)(ws + (16ull << 20));
  __bf16* vtb   = (__bf16*)(ws + (40ull << 20));
  __bf16* yb    = xb;

  cvt_all<<<4096, 256, 0, stream>>>(x, w_qkv, w_out, xb, wqkvb, wob);
  gemm_bt<1><<<dim3(QKVN / 128, NROWS / 128), 256, 0, stream>>>(xb, wqkvb, qkvb, vtb, NROWS, QKVN, EMB);
  attn_causal15<<<1024, 256, 0, stream>>>(qkvb, vtb, yb);
  gemm_bt<0><<<dim3(EMB / 128, NROWS / 128), 256, 0, stream>>>(yb, wob, out, nullptr, NROWS, EMB, EMB);
}

// Round 16
// 110.184 us; speedup vs baseline: 1.0101x; 1.0101x over previous
//
#include <hip/hip_runtime.h>
#include <hip/hip_bf16.h>
#include <cstdint>

// ---------------------------------------------------------------------------
// Fused causal self-attention block (B=2, T=2048, C=1024, H=16, Dh=64), fp32 in/out.
// cvt fp32->bf16 -> QKV GEMM (Q pre-scaled, V written transposed) -> flash attn -> out GEMM.
// Workspace (48MB):
//   yb    @ 0     8 MB   bf16 x (xb) -> DEAD after gemm1 -> reused as yb
//   wqkvb @ 8 MB  6 MB   bf16 w_qkv [3072][1024]
//   wob   @ 14MB  2 MB   bf16 w_out [1024][1024]
//   qkvb  @ 16MB 24 MB   bf16 qkv [4096][3072] (Q scaled | K | V-region unused)
//   vt    @ 40MB  8 MB   bf16 Vt [32 bh][64 d][2048 t] (written by gemm1 epilogue)
// ---------------------------------------------------------------------------

typedef __bf16 bf16x8 __attribute__((ext_vector_type(8)));
typedef float  f32x4  __attribute__((ext_vector_type(4)));
typedef unsigned short u16x4 __attribute__((ext_vector_type(4)));

#define EMB   1024
#define HEADS 16
#define HD    64
#define TT    2048
#define NROWS 4096
#define QKVN  3072
#define SCL   0.18033688f   /* 0.125 * log2(e): folded into Q at gemm1 epilogue */
#define THR   11.0f         /* defer-max threshold, log2 units */

// ---- fused fp32 -> bf16 (8 elems / thread, 3 arrays in one launch) ----
__global__ void cvt_all(const float* __restrict__ x, const float* __restrict__ wq,
                        const float* __restrict__ wo, __bf16* __restrict__ xb,
                        __bf16* __restrict__ wqb, __bf16* __restrict__ wob) {
  const int bid = blockIdx.x;
  const float* in; __bf16* out; int i;
  if (bid < 2048)      { in = x;  out = xb;  i = bid * 256 + threadIdx.x; }
  else if (bid < 3584) { in = wq; out = wqb; i = (bid - 2048) * 256 + threadIdx.x; }
  else                 { in = wo; out = wob; i = (bid - 3584) * 256 + threadIdx.x; }
  const float4* p = (const float4*)in + (size_t)i * 2;
  float4 a = p[0], b = p[1];
  bf16x8 o;
  o[0] = (__bf16)a.x; o[1] = (__bf16)a.y; o[2] = (__bf16)a.z; o[3] = (__bf16)a.w;
  o[4] = (__bf16)b.x; o[5] = (__bf16)b.y; o[6] = (__bf16)b.z; o[7] = (__bf16)b.w;
  *((bf16x8*)out + i) = o;
}

__device__ __forceinline__ void gload_lds16(const void* g, void* l) {
  __builtin_amdgcn_global_load_lds(
      (const __attribute__((address_space(1))) void*)(uintptr_t)g,
      (__attribute__((address_space(3))) void*)(uint32_t)(uintptr_t)l,
      16, 0, 0);
}

// ---------------------------------------------------------------------------
// GEMM (R12): 128x128 tile, BK=64, chunk-swizzled staging, XCD swizzle.
// MODE 1 epilogue: Q scaled, K plain, V transposed to vt.
// ---------------------------------------------------------------------------
template <int MODE>
__global__ __launch_bounds__(256, 2)
void gemm_bt(const __bf16* __restrict__ A, const __bf16* __restrict__ Bm,
             void* __restrict__ Cout, __bf16* __restrict__ vt,
             int M, int N, int K) {
  __shared__ __align__(16) char As[128 * 128];
  __shared__ __align__(16) char Bs[128 * 128];
  const int tid  = threadIdx.x;
  const int lane = tid & 63;
  const int wid  = tid >> 6;
  const int wr = wid >> 1, wc = wid & 1;
  const int nwg = gridDim.x * gridDim.y;
  int flat = blockIdx.y * gridDim.x + blockIdx.x;
  flat = (flat & 7) * (nwg >> 3) + (flat >> 3);
  const int brow = (flat / gridDim.x) * 128;
  const int bcol = (flat % gridDim.x) * 128;
  const int fr = lane & 15, g = lane >> 4;

  f32x4 acc[4][4];
#pragma unroll
  for (int m = 0; m < 4; m++)
#pragma unroll
    for (int n = 0; n < 4; n++)
#pragma unroll
      for (int r = 0; r < 4; r++) acc[m][n][r] = 0.0f;

  for (int k0 = 0; k0 < K; k0 += 64) {
    __syncthreads();
#pragma unroll
    for (int i = 0; i < 4; i++) {
      const int c = tid + i * 256;
      const int row = c >> 3, pos = c & 7;
      const int sc = pos ^ (row & 7);
      gload_lds16(A  + (size_t)(brow + row) * K + k0 + sc * 8, As + c * 16);
      gload_lds16(Bm + (size_t)(bcol + row) * K + k0 + sc * 8, Bs + c * 16);
    }
    __syncthreads();

    bf16x8 af[4][2], bfr[4][2];
#pragma unroll
    for (int m = 0; m < 4; m++)
#pragma unroll
      for (int kc = 0; kc < 2; kc++) {
        const int row = wr * 64 + m * 16 + fr;
        af[m][kc] = *(const bf16x8*)(As + row * 128 + (((kc << 2) | g) ^ (fr & 7)) * 16);
      }
#pragma unroll
    for (int n = 0; n < 4; n++)
#pragma unroll
      for (int kc = 0; kc < 2; kc++) {
        const int row = wc * 64 + n * 16 + fr;
        bfr[n][kc] = *(const bf16x8*)(Bs + row * 128 + (((kc << 2) | g) ^ (fr & 7)) * 16);
      }
#pragma unroll
    for (int kc = 0; kc < 2; kc++)
#pragma unroll
      for (int m = 0; m < 4; m++)
#pragma unroll
        for (int n = 0; n < 4; n++)
          acc[m][n] = __builtin_amdgcn_mfma_f32_16x16x32_bf16(af[m][kc], bfr[n][kc], acc[m][n], 0, 0, 0);
  }

  const int rbase = brow + wr * 64 + g * 4;
  const int cbase = bcol + wc * 64 + fr;
  if (MODE == 0) {
#pragma unroll
    for (int m = 0; m < 4; m++)
#pragma unroll
      for (int n = 0; n < 4; n++) {
        const int col = cbase + n * 16;
#pragma unroll
        for (int r = 0; r < 4; r++)
          ((float*)Cout)[(size_t)(rbase + m * 16 + r) * N + col] = acc[m][n][r];
      }
  } else if (bcol < 2 * EMB) {
    const float qscale = (bcol < EMB) ? SCL : 1.0f;
#pragma unroll
    for (int m = 0; m < 4; m++)
#pragma unroll
      for (int n = 0; n < 4; n++) {
        const int col = cbase + n * 16;
#pragma unroll
        for (int r = 0; r < 4; r++)
          ((__bf16*)Cout)[(size_t)(rbase + m * 16 + r) * N + col] = (__bf16)(acc[m][n][r] * qscale);
      }
  } else {
#pragma unroll
    for (int m = 0; m < 4; m++) {
      const int row0 = rbase + m * 16;
      const int b = row0 >> 11, t0 = row0 & 2047;
#pragma unroll
      for (int n = 0; n < 4; n++) {
        const int vcol = cbase + n * 16 - 2 * EMB;
        const int bh = b * HEADS + (vcol >> 6);
        const int d  = vcol & 63;
        u16x4 pk;
#pragma unroll
        for (int r = 0; r < 4; r++) {
          const __bf16 h = (__bf16)acc[m][n][r];
          pk[r] = *(const unsigned short*)&h;
        }
        *(u16x4*)(vt + ((size_t)bh * HD + d) * TT + t0) = pk;
      }
    }
  }
}

// ---------------------------------------------------------------------------
// Causal flash attention v16 = v13 (32-q-row waves, v9 pipeline) with a
// CORRECT constant-sum fold map.  grid 512 = 16 p x 32 bh, 2 blocks/CU:
// CU gets blocks L and L+256 -> p and p+8 -> chunks {p0, 15-p0} ->
// per-CU tile total = 34, constant (v13's LPT map gave 22 vs 8).
//   - Wave owns 32 q rows (2 m-frags); block = 128-row chunk; LDS ops per
//     unit work ~40% below v9 (kf/vb reads amortize over 2x rows).
//   - 4-deep K/V buffers, counted vmcnt(4); cross-tile pipeline
//     QK(t+1) | PV(t) | SM(t+1); per-wave tmaxw diagonal skip; defer-max;
//     ones-MFMA row-sum; raw v_exp_f32; Q pre-scaled; setprio on MFMA.
// LDS 80KB -> 2 blocks/CU, 8 waves/CU.
// ---------------------------------------------------------------------------
__device__ __forceinline__ int psw(int row) {
  return (((row & 7) ^ ((row >> 3) & 7))) << 4;
}

__global__ __launch_bounds__(256, 2)
void attn_causal16(const __bf16* __restrict__ qkv, const __bf16* __restrict__ vt,
                   __bf16* __restrict__ yb) {
  __shared__ __align__(16) char Kbuf[4][8192];   // K[kv][d], chunk-swizzled
  __shared__ __align__(16) char Vbuf[4][8192];   // Vt[d][kv], chunk-swizzled
  __shared__ __align__(16) char Pbuf[4][4096];   // per-wave P[32][64], psw-swizzled

  const int tid = threadIdx.x;
  const int lane = tid & 63, w = tid >> 6;
  const int L = blockIdx.x;
  const int bh = L & 31;
  const int p = L >> 5;                          // 0..15
  const int chunk = (p < 8) ? p : 23 - p;        // CU-pair {p,p+8} -> sum 34 tiles
  const int b = bh >> 4, h = bh & 15;
  const size_t rowbase = (size_t)b * TT;
  const int q0 = chunk * 128 + w * 32;           // wave's first q row
  const int fr = lane & 15, g = lane >> 4;
  const int ntiles = 2 * chunk + 2;
  const int tmaxw = (q0 + 31) >> 6;              // wave's last active tile

  bf16x8 qf[2][2];
#pragma unroll
  for (int m2 = 0; m2 < 2; m2++)
#pragma unroll
    for (int kc = 0; kc < 2; kc++)
      qf[m2][kc] = *(const bf16x8*)(qkv + (rowbase + q0 + m2 * 16 + fr) * QKVN + h * HD + kc * 32 + g * 8);

  bf16x8 ones;
#pragma unroll
  for (int j = 0; j < 8; j++) ones[j] = (__bf16)1.0f;

  f32x4 o[2][4];
  f32x4 lacc[2];
  float m[2][4];
#pragma unroll
  for (int m2 = 0; m2 < 2; m2++) {
#pragma unroll
    for (int n = 0; n < 4; n++)
#pragma unroll
      for (int r = 0; r < 4; r++) o[m2][n][r] = 0.0f;
#pragma unroll
    for (int r = 0; r < 4; r++) { lacc[m2][r] = 0.0f; m[m2][r] = -1e30f; }
  }

  // 4 gload_lds per thread per stage -> vmcnt(4) = one stage in flight
  auto stageKV = [&](int kt, int buf) {
#pragma unroll
    for (int i = 0; i < 2; i++) {
      const int c = tid + i * 256;
      const int row = c >> 3;
      const int c16 = (c & 7) ^ (row & 7);
      gload_lds16(qkv + (rowbase + kt * 64 + row) * QKVN + EMB + h * HD + c16 * 8,
                  Kbuf[buf] + c * 16);
    }
#pragma unroll
    for (int i = 0; i < 2; i++) {
      const int c = tid + i * 256;
      const int row = c >> 3;
      const int c16 = (c & 7) ^ (row & 7);
      gload_lds16(vt + ((size_t)bh * HD + row) * TT + kt * 64 + c16 * 8,
                  Vbuf[buf] + c * 16);
    }
  };

  auto doQK = [&](int kt, f32x4 (&s)[2][4]) {
    const char* Kc = Kbuf[kt & 3];
    bf16x8 kf[4][2];
#pragma unroll
    for (int n = 0; n < 4; n++)
#pragma unroll
      for (int kc = 0; kc < 2; kc++) {
        const int row = n * 16 + fr;
        kf[n][kc] = *(const bf16x8*)(Kc + row * 128 + (((kc << 2) | g) ^ (row & 7)) * 16);
      }
    __builtin_amdgcn_s_setprio(1);
#pragma unroll
    for (int m2 = 0; m2 < 2; m2++)
#pragma unroll
      for (int n = 0; n < 4; n++) {
#pragma unroll
        for (int r = 0; r < 4; r++) s[m2][n][r] = 0.0f;
#pragma unroll
        for (int kc = 0; kc < 2; kc++)
          s[m2][n] = __builtin_amdgcn_mfma_f32_16x16x32_bf16(qf[m2][kc], kf[n][kc], s[m2][n], 0, 0, 0);
      }
    __builtin_amdgcn_s_setprio(0);
  };

  auto doSoftmax = [&](int kt, f32x4 (&s)[2][4]) {
    const int kv0 = kt * 64;
    if (kt == tmaxw) {                           // diagonal tile for this wave
#pragma unroll
      for (int m2 = 0; m2 < 2; m2++)
#pragma unroll
        for (int n = 0; n < 4; n++)
#pragma unroll
          for (int r = 0; r < 4; r++) {
            const int qg = q0 + m2 * 16 + g * 4 + r;
            const int kg = kv0 + n * 16 + fr;
            if (kg > qg) s[m2][n][r] = -1e30f;
          }
    }
    float pm[2][4];
#pragma unroll
    for (int m2 = 0; m2 < 2; m2++)
#pragma unroll
      for (int r = 0; r < 4; r++)
        pm[m2][r] = fmaxf(fmaxf(s[m2][0][r], s[m2][1][r]), fmaxf(s[m2][2][r], s[m2][3][r]));
    bool okl = true;
#pragma unroll
    for (int m2 = 0; m2 < 2; m2++)
#pragma unroll
      for (int r = 0; r < 4; r++)
        okl = okl && (pm[m2][r] <= m[m2][r] + THR);
    if (!__all(okl)) {
#pragma unroll
      for (int m2 = 0; m2 < 2; m2++)
#pragma unroll
        for (int r = 0; r < 4; r++) {
          float rm = pm[m2][r];
#pragma unroll
          for (int d = 1; d < 16; d <<= 1) rm = fmaxf(rm, __shfl_xor(rm, d, 16));
          const float nm = fmaxf(m[m2][r], rm);
          const float f = __builtin_amdgcn_exp2f(m[m2][r] - nm);
          m[m2][r] = nm;
          lacc[m2][r] *= f;
#pragma unroll
          for (int n = 0; n < 4; n++) o[m2][n][r] *= f;
        }
    }
#pragma unroll
    for (int m2 = 0; m2 < 2; m2++)
#pragma unroll
      for (int n = 0; n < 4; n++)
#pragma unroll
        for (int r = 0; r < 4; r++) {
          const float e = __builtin_amdgcn_exp2f(s[m2][n][r] - m[m2][r]);
          const int row = m2 * 16 + g * 4 + r;
          *(__bf16*)(Pbuf[w] + row * 128 + (((n * 16 + fr) * 2) ^ psw(row))) = (__bf16)e;
        }
  };

  auto doPV = [&](int kt) {
    const char* Vc = Vbuf[kt & 3];
    bf16x8 pa[2][2];
#pragma unroll
    for (int m2 = 0; m2 < 2; m2++)
#pragma unroll
      for (int kc = 0; kc < 2; kc++) {
        const int row = m2 * 16 + fr;
        pa[m2][kc] = *(const bf16x8*)(Pbuf[w] + row * 128 + ((kc * 64 + g * 16) ^ psw(row)));
      }
    bf16x8 vb[4][2];
#pragma unroll
    for (int n = 0; n < 4; n++)
#pragma unroll
      for (int kc = 0; kc < 2; kc++) {
        const int row = n * 16 + fr;
        vb[n][kc] = *(const bf16x8*)(Vc + row * 128 + (((kc << 2) | g) ^ (row & 7)) * 16);
      }
    __builtin_amdgcn_s_setprio(1);
#pragma unroll
    for (int m2 = 0; m2 < 2; m2++)
#pragma unroll
      for (int kc = 0; kc < 2; kc++) {
        lacc[m2] = __builtin_amdgcn_mfma_f32_16x16x32_bf16(pa[m2][kc], ones, lacc[m2], 0, 0, 0);
#pragma unroll
        for (int n = 0; n < 4; n++)
          o[m2][n] = __builtin_amdgcn_mfma_f32_16x16x32_bf16(pa[m2][kc], vb[n][kc], o[m2][n], 0, 0, 0);
      }
    __builtin_amdgcn_s_setprio(0);
  };

  // ---- prologue: fill pipeline (tiles 0..2), force 0,1 landed ----
  stageKV(0, 0);
  if (ntiles > 1) stageKV(1, 1);
  if (ntiles > 2) stageKV(2, 2);
  if (ntiles > 2) asm volatile("s_waitcnt vmcnt(4)" ::: "memory");
  else            asm volatile("s_waitcnt vmcnt(0)" ::: "memory");
  __builtin_amdgcn_s_barrier();

  {                                   // tile 0: QK + softmax (all waves active)
    f32x4 s0[2][4];
    doQK(0, s0);
    doSoftmax(0, s0);
  }

  for (int t = 0; t < ntiles; t++) {
    if (t + 3 < ntiles) stageKV(t + 3, (t + 3) & 3);

    const bool nxt = (t + 1 < ntiles) && (t + 1 <= tmaxw);
    f32x4 s[2][4];
    if (nxt) doQK(t + 1, s);          // overlaps PV(t)
    if (t <= tmaxw) doPV(t);          // consumes P(t) written last iter
    if (nxt) doSoftmax(t + 1, s);     // rescale o AFTER PV(t); writes P(t+1)

    if (t + 3 < ntiles) asm volatile("s_waitcnt vmcnt(4)" ::: "memory");
    else                asm volatile("s_waitcnt vmcnt(0)" ::: "memory");
    __builtin_amdgcn_s_barrier();
  }

#pragma unroll
  for (int m2 = 0; m2 < 2; m2++)
#pragma unroll
    for (int r = 0; r < 4; r++) {
      const float inv = __builtin_amdgcn_rcpf(lacc[m2][r]);
      const int q = q0 + m2 * 16 + g * 4 + r;
#pragma unroll
      for (int n = 0; n < 4; n++) {
        const int d = n * 16 + fr;
        yb[(rowbase + q) * EMB + h * HD + d] = (__bf16)(o[m2][n][r] * inv);
      }
    }
}

extern "C" void kernel_launch(void* const* d_in, const int* in_sizes, int n_in,
                              void* d_out, int out_size, void* d_ws, size_t ws_size,
                              hipStream_t stream) {
  const float* x     = (const float*)d_in[0];
  const float* w_qkv = (const float*)d_in[1];
  const float* w_out = (const float*)d_in[2];
  float* out = (float*)d_out;

  char* ws = (char*)d_ws;
  __bf16* xb    = (__bf16*)(ws);                 // dead after gemm1 -> reused as yb
  __bf16* wqkvb = (__bf16*)(ws + (8ull  << 20));
  __bf16* wob   = (__bf16*)(ws + (14ull << 20));
  __bf16* qkvb  = (__bf16*)(ws + (16ull << 20));
  __bf16* vtb   = (__bf16*)(ws + (40ull << 20));
  __bf16* yb    = xb;

  cvt_all<<<4096, 256, 0, stream>>>(x, w_qkv, w_out, xb, wqkvb, wob);
  gemm_bt<1><<<dim3(QKVN / 128, NROWS / 128), 256, 0, stream>>>(xb, wqkvb, qkvb, vtb, NROWS, QKVN, EMB);
  attn_causal16<<<512, 256, 0, stream>>>(qkvb, vtb, yb);
  gemm_bt<0><<<dim3(EMB / 128, NROWS / 128), 256, 0, stream>>>(yb, wob, out, nullptr, NROWS, EMB, EMB);
}

// Round 18
// 102.413 us; speedup vs baseline: 1.0868x; 1.0759x over previous
//
#include <hip/hip_runtime.h>
#include <hip/hip_bf16.h>
#include <cstdint>

// ---------------------------------------------------------------------------
// Fused causal self-attention block (B=2, T=2048, C=1024, H=16, Dh=64), fp32 in/out.
// cvt fp32->bf16 -> QKV GEMM (Q pre-scaled, V written transposed) -> flash attn -> out GEMM.
// Workspace (48MB):
//   yb    @ 0     8 MB   bf16 x (xb) -> DEAD after gemm1 -> reused as yb
//   wqkvb @ 8 MB  6 MB   bf16 w_qkv [3072][1024]
//   wob   @ 14MB  2 MB   bf16 w_out [1024][1024]
//   qkvb  @ 16MB 24 MB   bf16 qkv [4096][3072] (Q scaled | K | V-region unused)
//   vt    @ 40MB  8 MB   bf16 Vt [32 bh][64 d][2048 t] (written by gemm1 epilogue)
// ---------------------------------------------------------------------------

typedef __bf16 bf16x8 __attribute__((ext_vector_type(8)));
typedef float  f32x4  __attribute__((ext_vector_type(4)));
typedef unsigned short u16x4 __attribute__((ext_vector_type(4)));

#define EMB   1024
#define HEADS 16
#define HD    64
#define TT    2048
#define NROWS 4096
#define QKVN  3072
#define SCL   0.18033688f   /* 0.125 * log2(e): folded into Q at gemm1 epilogue */
#define THR   11.0f         /* defer-max threshold, log2 units */

// ---- fused fp32 -> bf16 (8 elems / thread, 3 arrays in one launch) ----
__global__ void cvt_all(const float* __restrict__ x, const float* __restrict__ wq,
                        const float* __restrict__ wo, __bf16* __restrict__ xb,
                        __bf16* __restrict__ wqb, __bf16* __restrict__ wob) {
  const int bid = blockIdx.x;
  const float* in; __bf16* out; int i;
  if (bid < 2048)      { in = x;  out = xb;  i = bid * 256 + threadIdx.x; }
  else if (bid < 3584) { in = wq; out = wqb; i = (bid - 2048) * 256 + threadIdx.x; }
  else                 { in = wo; out = wob; i = (bid - 3584) * 256 + threadIdx.x; }
  const float4* p = (const float4*)in + (size_t)i * 2;
  float4 a = p[0], b = p[1];
  bf16x8 o;
  o[0] = (__bf16)a.x; o[1] = (__bf16)a.y; o[2] = (__bf16)a.z; o[3] = (__bf16)a.w;
  o[4] = (__bf16)b.x; o[5] = (__bf16)b.y; o[6] = (__bf16)b.z; o[7] = (__bf16)b.w;
  *((bf16x8*)out + i) = o;
}

__device__ __forceinline__ void gload_lds16(const void* g, void* l) {
  __builtin_amdgcn_global_load_lds(
      (const __attribute__((address_space(1))) void*)(uintptr_t)g,
      (__attribute__((address_space(3))) void*)(uint32_t)(uintptr_t)l,
      16, 0, 0);
}

// ---------------------------------------------------------------------------
// GEMM (R12): 128x128 tile, BK=64, chunk-swizzled staging, XCD swizzle.
// MODE 1 epilogue: Q scaled, K plain, V transposed to vt.
// ---------------------------------------------------------------------------
template <int MODE>
__global__ __launch_bounds__(256, 2)
void gemm_bt(const __bf16* __restrict__ A, const __bf16* __restrict__ Bm,
             void* __restrict__ Cout, __bf16* __restrict__ vt,
             int M, int N, int K) {
  __shared__ __align__(16) char As[128 * 128];
  __shared__ __align__(16) char Bs[128 * 128];
  const int tid  = threadIdx.x;
  const int lane = tid & 63;
  const int wid  = tid >> 6;
  const int wr = wid >> 1, wc = wid & 1;
  const int nwg = gridDim.x * gridDim.y;
  int flat = blockIdx.y * gridDim.x + blockIdx.x;
  flat = (flat & 7) * (nwg >> 3) + (flat >> 3);
  const int brow = (flat / gridDim.x) * 128;
  const int bcol = (flat % gridDim.x) * 128;
  const int fr = lane & 15, g = lane >> 4;

  f32x4 acc[4][4];
#pragma unroll
  for (int m = 0; m < 4; m++)
#pragma unroll
    for (int n = 0; n < 4; n++)
#pragma unroll
      for (int r = 0; r < 4; r++) acc[m][n][r] = 0.0f;

  for (int k0 = 0; k0 < K; k0 += 64) {
    __syncthreads();
#pragma unroll
    for (int i = 0; i < 4; i++) {
      const int c = tid + i * 256;
      const int row = c >> 3, pos = c & 7;
      const int sc = pos ^ (row & 7);
      gload_lds16(A  + (size_t)(brow + row) * K + k0 + sc * 8, As + c * 16);
      gload_lds16(Bm + (size_t)(bcol + row) * K + k0 + sc * 8, Bs + c * 16);
    }
    __syncthreads();

    bf16x8 af[4][2], bfr[4][2];
#pragma unroll
    for (int m = 0; m < 4; m++)
#pragma unroll
      for (int kc = 0; kc < 2; kc++) {
        const int row = wr * 64 + m * 16 + fr;
        af[m][kc] = *(const bf16x8*)(As + row * 128 + (((kc << 2) | g) ^ (fr & 7)) * 16);
      }
#pragma unroll
    for (int n = 0; n < 4; n++)
#pragma unroll
      for (int kc = 0; kc < 2; kc++) {
        const int row = wc * 64 + n * 16 + fr;
        bfr[n][kc] = *(const bf16x8*)(Bs + row * 128 + (((kc << 2) | g) ^ (fr & 7)) * 16);
      }
#pragma unroll
    for (int kc = 0; kc < 2; kc++)
#pragma unroll
      for (int m = 0; m < 4; m++)
#pragma unroll
        for (int n = 0; n < 4; n++)
          acc[m][n] = __builtin_amdgcn_mfma_f32_16x16x32_bf16(af[m][kc], bfr[n][kc], acc[m][n], 0, 0, 0);
  }

  const int rbase = brow + wr * 64 + g * 4;
  const int cbase = bcol + wc * 64 + fr;
  if (MODE == 0) {
#pragma unroll
    for (int m = 0; m < 4; m++)
#pragma unroll
      for (int n = 0; n < 4; n++) {
        const int col = cbase + n * 16;
#pragma unroll
        for (int r = 0; r < 4; r++)
          ((float*)Cout)[(size_t)(rbase + m * 16 + r) * N + col] = acc[m][n][r];
      }
  } else if (bcol < 2 * EMB) {
    const float qscale = (bcol < EMB) ? SCL : 1.0f;
#pragma unroll
    for (int m = 0; m < 4; m++)
#pragma unroll
      for (int n = 0; n < 4; n++) {
        const int col = cbase + n * 16;
#pragma unroll
        for (int r = 0; r < 4; r++)
          ((__bf16*)Cout)[(size_t)(rbase + m * 16 + r) * N + col] = (__bf16)(acc[m][n][r] * qscale);
      }
  } else {
#pragma unroll
    for (int m = 0; m < 4; m++) {
      const int row0 = rbase + m * 16;
      const int b = row0 >> 11, t0 = row0 & 2047;
#pragma unroll
      for (int n = 0; n < 4; n++) {
        const int vcol = cbase + n * 16 - 2 * EMB;
        const int bh = b * HEADS + (vcol >> 6);
        const int d  = vcol & 63;
        u16x4 pk;
#pragma unroll
        for (int r = 0; r < 4; r++) {
          const __bf16 h = (__bf16)acc[m][n][r];
          pk[r] = *(const unsigned short*)&h;
        }
        *(u16x4*)(vt + ((size_t)bh * HD + d) * TT + t0) = pk;
      }
    }
  }
}

// ---------------------------------------------------------------------------
// Causal flash attention (v9 + T5 setprio): cross-tile software pipeline.
//   Iter t: stage(t+3) | QK(t+1) | PV(t) | softmax(t+1)+P-write(t+1).
//   4-deep K/V LDS buffers, counted s_waitcnt vmcnt(4) (never 0 in steady
//   state); raw v_exp_f32; defer-max vote; row-sum via ones-MFMA;
//   Q pre-scaled at gemm1.  s_setprio(1) wraps the QK and PV MFMA clusters
//   (T5: our pipeline has load-issuing vs MFMA-entering wave role-split).
// grid = 1024 (32 chunks x 32 bh), LPT order.  LDS 72KB -> 2 blocks/CU.
// ---------------------------------------------------------------------------
__device__ __forceinline__ int psw(int row) {
  return (((row & 7) ^ ((row >> 3) & 7))) << 4;
}

__global__ __launch_bounds__(256, 2)
void attn_causal9(const __bf16* __restrict__ qkv, const __bf16* __restrict__ vt,
                  __bf16* __restrict__ yb) {
  __shared__ __align__(16) char Kbuf[4][8192];   // K[kv][d], chunk-swizzled
  __shared__ __align__(16) char Vbuf[4][8192];   // Vt[d][kv], chunk-swizzled
  __shared__ __align__(16) char Pbuf[4][2048];   // per-wave P[16][64], psw-swizzled

  const int tid = threadIdx.x;
  const int lane = tid & 63, w = tid >> 6;
  const int L = blockIdx.x;
  const int bh = L & 31;
  const int chunk = 31 - (L >> 5);               // LPT: longest first
  const int b = bh >> 4, h = bh & 15;
  const size_t rowbase = (size_t)b * TT;
  const int q0 = chunk * 64 + w * 16;
  const int fr = lane & 15, g = lane >> 4;
  const int ntiles = chunk + 1;

  bf16x8 qf[2];
#pragma unroll
  for (int kc = 0; kc < 2; kc++)
    qf[kc] = *(const bf16x8*)(qkv + (rowbase + q0 + fr) * QKVN + h * HD + kc * 32 + g * 8);

  bf16x8 ones;
#pragma unroll
  for (int j = 0; j < 8; j++) ones[j] = (__bf16)1.0f;

  f32x4 o[4];
  f32x4 lacc;
  float m[4];
#pragma unroll
  for (int n = 0; n < 4; n++)
#pragma unroll
    for (int r = 0; r < 4; r++) o[n][r] = 0.0f;
#pragma unroll
  for (int r = 0; r < 4; r++) { lacc[r] = 0.0f; m[r] = -1e30f; }

  auto stageKV = [&](int kt, int buf) {
#pragma unroll
    for (int i = 0; i < 2; i++) {
      const int c = tid + i * 256;
      const int row = c >> 3;
      const int c16 = (c & 7) ^ (row & 7);
      gload_lds16(qkv + (rowbase + kt * 64 + row) * QKVN + EMB + h * HD + c16 * 8,
                  Kbuf[buf] + c * 16);
    }
#pragma unroll
    for (int i = 0; i < 2; i++) {
      const int c = tid + i * 256;
      const int row = c >> 3;
      const int c16 = (c & 7) ^ (row & 7);
      gload_lds16(vt + ((size_t)bh * HD + row) * TT + kt * 64 + c16 * 8,
                  Vbuf[buf] + c * 16);
    }
  };

  auto doQK = [&](int kt, f32x4 (&s)[4]) {
    const char* Kc = Kbuf[kt & 3];
    bf16x8 kf[4][2];
#pragma unroll
    for (int n = 0; n < 4; n++)
#pragma unroll
      for (int kc = 0; kc < 2; kc++) {
        const int row = n * 16 + fr;
        kf[n][kc] = *(const bf16x8*)(Kc + row * 128 + (((kc << 2) | g) ^ (row & 7)) * 16);
      }
    __builtin_amdgcn_s_setprio(1);
#pragma unroll
    for (int n = 0; n < 4; n++) {
#pragma unroll
      for (int r = 0; r < 4; r++) s[n][r] = 0.0f;
#pragma unroll
      for (int kc = 0; kc < 2; kc++)
        s[n] = __builtin_amdgcn_mfma_f32_16x16x32_bf16(qf[kc], kf[n][kc], s[n], 0, 0, 0);
    }
    __builtin_amdgcn_s_setprio(0);
  };

  auto doSoftmax = [&](int kt, f32x4 (&s)[4]) {
    const int kv0 = kt * 64;
    if (kt == chunk) {
#pragma unroll
      for (int n = 0; n < 4; n++)
#pragma unroll
        for (int r = 0; r < 4; r++) {
          const int qg = q0 + g * 4 + r;
          const int kg = kv0 + n * 16 + fr;
          if (kg > qg) s[n][r] = -1e30f;
        }
    }
    float pm[4];
#pragma unroll
    for (int r = 0; r < 4; r++)
      pm[r] = fmaxf(fmaxf(s[0][r], s[1][r]), fmaxf(s[2][r], s[3][r]));
    const bool ok = (pm[0] <= m[0] + THR) && (pm[1] <= m[1] + THR) &&
                    (pm[2] <= m[2] + THR) && (pm[3] <= m[3] + THR);
    if (!__all(ok)) {
#pragma unroll
      for (int r = 0; r < 4; r++) {
        float rm = pm[r];
#pragma unroll
        for (int d = 1; d < 16; d <<= 1) rm = fmaxf(rm, __shfl_xor(rm, d, 16));
        const float nm = fmaxf(m[r], rm);
        const float f = __builtin_amdgcn_exp2f(m[r] - nm);
        m[r] = nm;
        lacc[r] *= f;
#pragma unroll
        for (int n = 0; n < 4; n++) o[n][r] *= f;
      }
    }
#pragma unroll
    for (int n = 0; n < 4; n++)
#pragma unroll
      for (int r = 0; r < 4; r++) {
        const float e = __builtin_amdgcn_exp2f(s[n][r] - m[r]);
        const int row = g * 4 + r;
        *(__bf16*)(Pbuf[w] + row * 128 + (((n * 16 + fr) * 2) ^ psw(row))) = (__bf16)e;
      }
  };

  auto doPV = [&](int kt) {
    const char* Vc = Vbuf[kt & 3];
    bf16x8 pa[2];
#pragma unroll
    for (int kc = 0; kc < 2; kc++)
      pa[kc] = *(const bf16x8*)(Pbuf[w] + fr * 128 + ((kc * 64 + g * 16) ^ psw(fr)));
    bf16x8 vb[4][2];
#pragma unroll
    for (int n = 0; n < 4; n++)
#pragma unroll
      for (int kc = 0; kc < 2; kc++) {
        const int row = n * 16 + fr;
        vb[n][kc] = *(const bf16x8*)(Vc + row * 128 + (((kc << 2) | g) ^ (row & 7)) * 16);
      }
    __builtin_amdgcn_s_setprio(1);
#pragma unroll
    for (int kc = 0; kc < 2; kc++) {
      lacc = __builtin_amdgcn_mfma_f32_16x16x32_bf16(pa[kc], ones, lacc, 0, 0, 0);
#pragma unroll
      for (int n = 0; n < 4; n++)
        o[n] = __builtin_amdgcn_mfma_f32_16x16x32_bf16(pa[kc], vb[n][kc], o[n], 0, 0, 0);
    }
    __builtin_amdgcn_s_setprio(0);
  };

  // ---- prologue: fill pipeline (tiles 0..2), force 0,1 landed ----
  stageKV(0, 0);
  if (ntiles > 1) stageKV(1, 1);
  if (ntiles > 2) stageKV(2, 2);
  if (ntiles > 2) asm volatile("s_waitcnt vmcnt(4)" ::: "memory");
  else            asm volatile("s_waitcnt vmcnt(0)" ::: "memory");
  __builtin_amdgcn_s_barrier();

  {                                   // tile 0: QK + softmax (P ready for loop)
    f32x4 s0[4];
    doQK(0, s0);
    doSoftmax(0, s0);
  }

  for (int t = 0; t < ntiles; t++) {
    if (t + 3 < ntiles) stageKV(t + 3, (t + 3) & 3);

    const bool nxt = (t + 1 < ntiles);
    f32x4 s[4];
    if (nxt) doQK(t + 1, s);          // independent stream: overlaps PV(t)
    doPV(t);                          // consumes P(t) written last iter
    if (nxt) doSoftmax(t + 1, s);     // rescale o AFTER PV(t); writes P(t+1)

    if (t + 3 < ntiles) asm volatile("s_waitcnt vmcnt(4)" ::: "memory");
    else                asm volatile("s_waitcnt vmcnt(0)" ::: "memory");
    __builtin_amdgcn_s_barrier();
  }

#pragma unroll
  for (int r = 0; r < 4; r++) {
    const float inv = __builtin_amdgcn_rcpf(lacc[r]);
#pragma unroll
    for (int n = 0; n < 4; n++) {
      const int q = q0 + g * 4 + r;
      const int d = n * 16 + fr;
      yb[(rowbase + q) * EMB + h * HD + d] = (__bf16)(o[n][r] * inv);
    }
  }
}

extern "C" void kernel_launch(void* const* d_in, const int* in_sizes, int n_in,
                              void* d_out, int out_size, void* d_ws, size_t ws_size,
                              hipStream_t stream) {
  const float* x     = (const float*)d_in[0];
  const float* w_qkv = (const float*)d_in[1];
  const float* w_out = (const float*)d_in[2];
  float* out = (float*)d_out;

  char* ws = (char*)d_ws;
  __bf16* xb    = (__bf16*)(ws);                 // dead after gemm1 -> reused as yb
  __bf16* wqkvb = (__bf16*)(ws + (8ull  << 20));
  __bf16* wob   = (__bf16*)(ws + (14ull << 20));
  __bf16* qkvb  = (__bf16*)(ws + (16ull << 20));
  __bf16* vtb   = (__bf16*)(ws + (40ull << 20));
  __bf16* yb    = xb;

  cvt_all<<<4096, 256, 0, stream>>>(x, w_qkv, w_out, xb, wqkvb, wob);
  // QKV GEMM: writes Q (scaled) + K to qkvb, V transposed to vtb
  gemm_bt<1><<<dim3(QKVN / 128, NROWS / 128), 256, 0, stream>>>(xb, wqkvb, qkvb, vtb, NROWS, QKVN, EMB);
  attn_causal9<<<1024, 256, 0, stream>>>(qkvb, vtb, yb);
  gemm_bt<0><<<dim3(EMB / 128, NROWS / 128), 256, 0, stream>>>(yb, wob, out, nullptr, NROWS, EMB, EMB);
}

// Round 19
// 98.099 us; speedup vs baseline: 1.1346x; 1.0440x over previous
//
#include <hip/hip_runtime.h>
#include <hip/hip_bf16.h>
#include <cstdint>

// ---------------------------------------------------------------------------
// Fused causal self-attention block (B=2, T=2048, C=1024, H=16, Dh=64), fp32 in/out.
// cvt fp32->bf16 -> QKV GEMM (Q pre-scaled, V written transposed) -> flash attn -> out GEMM.
// Workspace (48MB):
//   yb    @ 0     8 MB   bf16 x (xb) -> DEAD after gemm1 -> reused as yb
//   wqkvb @ 8 MB  6 MB   bf16 w_qkv [3072][1024]
//   wob   @ 14MB  2 MB   bf16 w_out [1024][1024]
//   qkvb  @ 16MB 24 MB   bf16 qkv [4096][3072] (Q scaled | K | V-region unused)
//   vt    @ 40MB  8 MB   bf16 Vt [32 bh][64 d][2048 t] (written by gemm1 epilogue)
// ---------------------------------------------------------------------------

typedef __bf16 bf16x8 __attribute__((ext_vector_type(8)));
typedef float  f32x4  __attribute__((ext_vector_type(4)));
typedef unsigned short u16x4 __attribute__((ext_vector_type(4)));
typedef unsigned int   u32x4 __attribute__((ext_vector_type(4)));

#define EMB   1024
#define HEADS 16
#define HD    64
#define TT    2048
#define NROWS 4096
#define QKVN  3072
#define SCL   0.18033688f   /* 0.125 * log2(e): folded into Q at gemm1 epilogue */
#define THR   11.0f         /* defer-max threshold, log2 units */

// ---- fused fp32 -> bf16 (8 elems / thread, 3 arrays in one launch) ----
__global__ void cvt_all(const float* __restrict__ x, const float* __restrict__ wq,
                        const float* __restrict__ wo, __bf16* __restrict__ xb,
                        __bf16* __restrict__ wqb, __bf16* __restrict__ wob) {
  const int bid = blockIdx.x;
  const float* in; __bf16* out; int i;
  if (bid < 2048)      { in = x;  out = xb;  i = bid * 256 + threadIdx.x; }
  else if (bid < 3584) { in = wq; out = wqb; i = (bid - 2048) * 256 + threadIdx.x; }
  else                 { in = wo; out = wob; i = (bid - 3584) * 256 + threadIdx.x; }
  const float4* p = (const float4*)in + (size_t)i * 2;
  float4 a = p[0], b = p[1];
  bf16x8 o;
  o[0] = (__bf16)a.x; o[1] = (__bf16)a.y; o[2] = (__bf16)a.z; o[3] = (__bf16)a.w;
  o[4] = (__bf16)b.x; o[5] = (__bf16)b.y; o[6] = (__bf16)b.z; o[7] = (__bf16)b.w;
  *((bf16x8*)out + i) = o;
}

__device__ __forceinline__ void gload_lds16(const void* g, void* l) {
  __builtin_amdgcn_global_load_lds(
      (const __attribute__((address_space(1))) void*)(uintptr_t)g,
      (__attribute__((address_space(3))) void*)(uint32_t)(uintptr_t)l,
      16, 0, 0);
}

// ---------------------------------------------------------------------------
// GEMM (R12): 128x128 tile, BK=64, chunk-swizzled staging, XCD swizzle.
// MODE 1 epilogue: Q scaled, K plain, V transposed to vt.
// ---------------------------------------------------------------------------
template <int MODE>
__global__ __launch_bounds__(256, 2)
void gemm_bt(const __bf16* __restrict__ A, const __bf16* __restrict__ Bm,
             void* __restrict__ Cout, __bf16* __restrict__ vt,
             int M, int N, int K) {
  __shared__ __align__(16) char As[128 * 128];
  __shared__ __align__(16) char Bs[128 * 128];
  const int tid  = threadIdx.x;
  const int lane = tid & 63;
  const int wid  = tid >> 6;
  const int wr = wid >> 1, wc = wid & 1;
  const int nwg = gridDim.x * gridDim.y;
  int flat = blockIdx.y * gridDim.x + blockIdx.x;
  flat = (flat & 7) * (nwg >> 3) + (flat >> 3);
  const int brow = (flat / gridDim.x) * 128;
  const int bcol = (flat % gridDim.x) * 128;
  const int fr = lane & 15, g = lane >> 4;

  f32x4 acc[4][4];
#pragma unroll
  for (int m = 0; m < 4; m++)
#pragma unroll
    for (int n = 0; n < 4; n++)
#pragma unroll
      for (int r = 0; r < 4; r++) acc[m][n][r] = 0.0f;

  for (int k0 = 0; k0 < K; k0 += 64) {
    __syncthreads();
#pragma unroll
    for (int i = 0; i < 4; i++) {
      const int c = tid + i * 256;
      const int row = c >> 3, pos = c & 7;
      const int sc = pos ^ (row & 7);
      gload_lds16(A  + (size_t)(brow + row) * K + k0 + sc * 8, As + c * 16);
      gload_lds16(Bm + (size_t)(bcol + row) * K + k0 + sc * 8, Bs + c * 16);
    }
    __syncthreads();

    bf16x8 af[4][2], bfr[4][2];
#pragma unroll
    for (int m = 0; m < 4; m++)
#pragma unroll
      for (int kc = 0; kc < 2; kc++) {
        const int row = wr * 64 + m * 16 + fr;
        af[m][kc] = *(const bf16x8*)(As + row * 128 + (((kc << 2) | g) ^ (fr & 7)) * 16);
      }
#pragma unroll
    for (int n = 0; n < 4; n++)
#pragma unroll
      for (int kc = 0; kc < 2; kc++) {
        const int row = wc * 64 + n * 16 + fr;
        bfr[n][kc] = *(const bf16x8*)(Bs + row * 128 + (((kc << 2) | g) ^ (fr & 7)) * 16);
      }
#pragma unroll
    for (int kc = 0; kc < 2; kc++)
#pragma unroll
      for (int m = 0; m < 4; m++)
#pragma unroll
        for (int n = 0; n < 4; n++)
          acc[m][n] = __builtin_amdgcn_mfma_f32_16x16x32_bf16(af[m][kc], bfr[n][kc], acc[m][n], 0, 0, 0);
  }

  const int rbase = brow + wr * 64 + g * 4;
  const int cbase = bcol + wc * 64 + fr;
  if (MODE == 0) {
#pragma unroll
    for (int m = 0; m < 4; m++)
#pragma unroll
      for (int n = 0; n < 4; n++) {
        const int col = cbase + n * 16;
#pragma unroll
        for (int r = 0; r < 4; r++)
          ((float*)Cout)[(size_t)(rbase + m * 16 + r) * N + col] = acc[m][n][r];
      }
  } else if (bcol < 2 * EMB) {
    const float qscale = (bcol < EMB) ? SCL : 1.0f;
#pragma unroll
    for (int m = 0; m < 4; m++)
#pragma unroll
      for (int n = 0; n < 4; n++) {
        const int col = cbase + n * 16;
#pragma unroll
        for (int r = 0; r < 4; r++)
          ((__bf16*)Cout)[(size_t)(rbase + m * 16 + r) * N + col] = (__bf16)(acc[m][n][r] * qscale);
      }
  } else {
#pragma unroll
    for (int m = 0; m < 4; m++) {
      const int row0 = rbase + m * 16;
      const int b = row0 >> 11, t0 = row0 & 2047;
#pragma unroll
      for (int n = 0; n < 4; n++) {
        const int vcol = cbase + n * 16 - 2 * EMB;
        const int bh = b * HEADS + (vcol >> 6);
        const int d  = vcol & 63;
        u16x4 pk;
#pragma unroll
        for (int r = 0; r < 4; r++) {
          const __bf16 h = (__bf16)acc[m][n][r];
          pk[r] = *(const unsigned short*)&h;
        }
        *(u16x4*)(vt + ((size_t)bh * HD + d) * TT + t0) = pk;
      }
    }
  }
}

// ---------------------------------------------------------------------------
// Causal flash attention v18 = v15 (swapped QK^T, in-register softmax, PASSED
// correctness) with cross-lane traffic on the VALU pipe via permlane swaps.
// v17's failure root-cause: reduction operands seeded with the SAME value
// were CSE'd into one VGPR -> self-swap + fmax degenerated.  Fix: opaque
// v_mov copy before each self-swap (forces distinct registers).
// Routing identity (verified, and v15's shfl version passed):
//   (A,B)=(pk[2kc][w2], pk[2kc+1][w2]); swap32(A,B); swap16(A,B)
//   => A=[A_g0,A_g2,B_g0,B_g2]=bw[w2], B=[A_g1,A_g3,B_g1,B_g3]=bw[w2+2].
// LDS per wave-tile: ONLY 16 ds_read_b128 (kf+vb).  4-deep K/V buffers,
// counted vmcnt(4); grid 1024 (32 chunks x 32 bh), LPT.  LDS 64KB.
// ---------------------------------------------------------------------------
__device__ __forceinline__ int psw(int row) {
  return (((row & 7) ^ ((row >> 3) & 7))) << 4;
}

__device__ __forceinline__ unsigned int pack_bf16(float a, float b) {
  const __bf16 ha = (__bf16)a, hb = (__bf16)b;
  const unsigned short ua = *(const unsigned short*)&ha;
  const unsigned short ub = *(const unsigned short*)&hb;
  return (unsigned int)ua | ((unsigned int)ub << 16);
}

__device__ __forceinline__ float opaque_f(float x) {
  float y;
  asm volatile("v_mov_b32 %0, %1" : "=v"(y) : "v"(x));
  return y;
}

__global__ __launch_bounds__(256, 2)
void attn_causal18(const __bf16* __restrict__ qkv, const __bf16* __restrict__ vt,
                   __bf16* __restrict__ yb) {
  __shared__ __align__(16) char Kbuf[4][8192];   // K[kv][d], chunk-swizzled
  __shared__ __align__(16) char Vbuf[4][8192];   // Vt[d][kv], chunk-swizzled

  const int tid = threadIdx.x;
  const int lane = tid & 63, w = tid >> 6;
  const int L = blockIdx.x;
  const int bh = L & 31;
  const int chunk = 31 - (L >> 5);               // LPT: longest first
  const int b = bh >> 4, h = bh & 15;
  const size_t rowbase = (size_t)b * TT;
  const int q0 = chunk * 64 + w * 16;
  const int fr = lane & 15, g = lane >> 4;
  const int ntiles = chunk + 1;

  bf16x8 qf[2];
#pragma unroll
  for (int kc = 0; kc < 2; kc++)
    qf[kc] = *(const bf16x8*)(qkv + (rowbase + q0 + fr) * QKVN + h * HD + kc * 32 + g * 8);

  f32x4 o[4];            // O^T frags: lane q=q0+fr holds d = n*16 + g*4 + r
  float lacc = 0.0f;     // row sum (scalar per lane)
  float ml = -1e30f;     // running max (scalar per lane)
#pragma unroll
  for (int n = 0; n < 4; n++)
#pragma unroll
    for (int r = 0; r < 4; r++) o[n][r] = 0.0f;

  auto stageKV = [&](int kt, int buf) {
#pragma unroll
    for (int i = 0; i < 2; i++) {
      const int c = tid + i * 256;
      const int row = c >> 3;
      const int c16 = (c & 7) ^ (row & 7);
      gload_lds16(qkv + (rowbase + kt * 64 + row) * QKVN + EMB + h * HD + c16 * 8,
                  Kbuf[buf] + c * 16);
    }
#pragma unroll
    for (int i = 0; i < 2; i++) {
      const int c = tid + i * 256;
      const int row = c >> 3;
      const int c16 = (c & 7) ^ (row & 7);
      gload_lds16(vt + ((size_t)bh * HD + row) * TT + kt * 64 + c16 * 8,
                  Vbuf[buf] + c * 16);
    }
  };

  // S^T = mfma(A=K, B=Q): s[n][r] = S[q=q0+fr][kv = kt*64 + n*16 + g*4 + r]
  auto doQK = [&](int kt, f32x4 (&s)[4]) {
    const char* Kc = Kbuf[kt & 3];
    bf16x8 kf[4][2];
#pragma unroll
    for (int n = 0; n < 4; n++)
#pragma unroll
      for (int kc = 0; kc < 2; kc++) {
        const int row = n * 16 + fr;
        kf[n][kc] = *(const bf16x8*)(Kc + row * 128 + (((kc << 2) | g) ^ (row & 7)) * 16);
      }
    __builtin_amdgcn_s_setprio(1);
#pragma unroll
    for (int n = 0; n < 4; n++) {
#pragma unroll
      for (int r = 0; r < 4; r++) s[n][r] = 0.0f;
#pragma unroll
      for (int kc = 0; kc < 2; kc++)
        s[n] = __builtin_amdgcn_mfma_f32_16x16x32_bf16(kf[n][kc], qf[kc], s[n], 0, 0, 0);
    }
    __builtin_amdgcn_s_setprio(0);
  };

  // in-register softmax + P^T B-operand assembly via permlane swaps (VALU)
  auto doSM = [&](int kt, f32x4 (&s)[4], bf16x8 (&pb)[2]) {
    const int kv0 = kt * 64;
    if (kt == chunk) {                           // causal mask, diagonal tile
      const int qg = q0 + fr;
#pragma unroll
      for (int n = 0; n < 4; n++)
#pragma unroll
        for (int r = 0; r < 4; r++) {
          const int kg = kv0 + n * 16 + g * 4 + r;
          if (kg > qg) s[n][r] = -1e30f;
        }
    }
    // per-lane max over 16 values, then across the 4 g-groups (VALU swaps,
    // opaque copies force distinct registers for the self-swaps)
    float pm = s[0][0];
#pragma unroll
    for (int n = 0; n < 4; n++)
#pragma unroll
      for (int r = 0; r < 4; r++) pm = fmaxf(pm, s[n][r]);
    {
      float c16 = opaque_f(pm);
      asm("v_permlane16_swap_b32 %0, %1" : "+v"(pm), "+v"(c16));
      pm = fmaxf(pm, c16);                       // pairwise max (g0<->g1, g2<->g3)
      float c32 = opaque_f(pm);
      asm("v_permlane32_swap_b32 %0, %1" : "+v"(pm), "+v"(c32));
      pm = fmaxf(pm, c32);                       // cross-half -> full 4-group max
    }
    if (!__all(pm <= ml + THR)) {
      const float nm = fmaxf(ml, pm);
      const float f = __builtin_amdgcn_exp2f(ml - nm);
      ml = nm;
      lacc *= f;
#pragma unroll
      for (int n = 0; n < 4; n++)
#pragma unroll
        for (int r = 0; r < 4; r++) o[n][r] *= f;
    }
    float p[4][4];
    float ts = 0.0f;
#pragma unroll
    for (int n = 0; n < 4; n++)
#pragma unroll
      for (int r = 0; r < 4; r++) {
        p[n][r] = __builtin_amdgcn_exp2f(s[n][r] - ml);
        ts += p[n][r];
      }
    {
      float c16 = opaque_f(ts);
      asm("v_permlane16_swap_b32 %0, %1" : "+v"(ts), "+v"(c16));
      ts = ts + c16;
      float c32 = opaque_f(ts);
      asm("v_permlane32_swap_b32 %0, %1" : "+v"(ts), "+v"(c32));
      ts = ts + c32;
    }
    lacc += ts;
    // pack adjacent-kv pairs: pk[n][w2] = bf16(p[n][2w2]) | bf16(p[n][2w2+1])<<16
    unsigned int pk[4][2];
#pragma unroll
    for (int n = 0; n < 4; n++)
#pragma unroll
      for (int w2 = 0; w2 < 2; w2++)
        pk[n][w2] = pack_bf16(p[n][2 * w2], p[n][2 * w2 + 1]);
    // route to B-frag via permlane swaps (distinct inputs -> no CSE hazard)
#pragma unroll
    for (int kc = 0; kc < 2; kc++) {
      unsigned int a0 = pk[2 * kc][0], b0 = pk[2 * kc + 1][0];
      asm("v_permlane32_swap_b32 %0, %1" : "+v"(a0), "+v"(b0));
      asm("v_permlane16_swap_b32 %0, %1" : "+v"(a0), "+v"(b0));
      unsigned int a1 = pk[2 * kc][1], b1 = pk[2 * kc + 1][1];
      asm("v_permlane32_swap_b32 %0, %1" : "+v"(a1), "+v"(b1));
      asm("v_permlane16_swap_b32 %0, %1" : "+v"(a1), "+v"(b1));
      u32x4 bw;
      bw[0] = a0; bw[1] = a1; bw[2] = b0; bw[3] = b1;
      pb[kc] = *(bf16x8*)&bw;
    }
  };

  // O^T += mfma(A=Vt frag, B=P^T)
  auto doPV = [&](int kt, bf16x8 (&pb)[2]) {
    const char* Vc = Vbuf[kt & 3];
    bf16x8 vb[4][2];
#pragma unroll
    for (int n = 0; n < 4; n++)
#pragma unroll
      for (int kc = 0; kc < 2; kc++) {
        const int row = n * 16 + fr;
        vb[n][kc] = *(const bf16x8*)(Vc + row * 128 + (((kc << 2) | g) ^ (row & 7)) * 16);
      }
    __builtin_amdgcn_s_setprio(1);
#pragma unroll
    for (int kc = 0; kc < 2; kc++)
#pragma unroll
      for (int n = 0; n < 4; n++)
        o[n] = __builtin_amdgcn_mfma_f32_16x16x32_bf16(vb[n][kc], pb[kc], o[n], 0, 0, 0);
    __builtin_amdgcn_s_setprio(0);
  };

  // ---- prologue: fill pipeline (tiles 0..2), force 0,1 landed ----
  stageKV(0, 0);
  if (ntiles > 1) stageKV(1, 1);
  if (ntiles > 2) stageKV(2, 2);
  if (ntiles > 2) asm volatile("s_waitcnt vmcnt(4)" ::: "memory");
  else            asm volatile("s_waitcnt vmcnt(0)" ::: "memory");
  __builtin_amdgcn_s_barrier();

  bf16x8 pb[2];
  {                                   // tile 0: QK + softmax (pb ready)
    f32x4 s0[4];
    doQK(0, s0);
    doSM(0, s0, pb);
  }

  for (int t = 0; t < ntiles; t++) {
    if (t + 3 < ntiles) stageKV(t + 3, (t + 3) & 3);

    const bool nxt = (t + 1 < ntiles);
    f32x4 s[4];
    if (nxt) doQK(t + 1, s);          // overlaps PV(t)
    doPV(t, pb);                      // consumes pb(t)
    if (nxt) doSM(t + 1, s, pb);      // rescale o AFTER PV(t); makes pb(t+1)

    if (t + 3 < ntiles) asm volatile("s_waitcnt vmcnt(4)" ::: "memory");
    else                asm volatile("s_waitcnt vmcnt(0)" ::: "memory");
    __builtin_amdgcn_s_barrier();
  }

  // ---- epilogue: O^T -> [q][d] via per-wave LDS region (Kbuf dead) ----
  {
    char* Tw = (char*)Kbuf + w * 2048;           // [16 q][64 d] bf16, psw-swizzled
    const float inv = __builtin_amdgcn_rcpf(lacc);
#pragma unroll
    for (int n = 0; n < 4; n++)
#pragma unroll
      for (int r = 0; r < 4; r++) {
        const int d = n * 16 + g * 4 + r;
        *(__bf16*)(Tw + fr * 128 + ((d * 2) ^ psw(fr))) = (__bf16)(o[n][r] * inv);
      }
#pragma unroll
    for (int i = 0; i < 2; i++) {
      const int c = lane + i * 64;               // 128 16B-chunks
      const int row = c >> 3, pos = c & 7;
      const bf16x8 v = *(const bf16x8*)(Tw + row * 128 + ((pos * 16) ^ psw(row)));
      *(bf16x8*)(yb + (rowbase + q0 + row) * EMB + h * HD + pos * 8) = v;
    }
  }
}

extern "C" void kernel_launch(void* const* d_in, const int* in_sizes, int n_in,
                              void* d_out, int out_size, void* d_ws, size_t ws_size,
                              hipStream_t stream) {
  const float* x     = (const float*)d_in[0];
  const float* w_qkv = (const float*)d_in[1];
  const float* w_out = (const float*)d_in[2];
  float* out = (float*)d_out;

  char* ws = (char*)d_ws;
  __bf16* xb    = (__bf16*)(ws);                 // dead after gemm1 -> reused as yb
  __bf16* wqkvb = (__bf16*)(ws + (8ull  << 20));
  __bf16* wob   = (__bf16*)(ws + (14ull << 20));
  __bf16* qkvb  = (__bf16*)(ws + (16ull << 20));
  __bf16* vtb   = (__bf16*)(ws + (40ull << 20));
  __bf16* yb    = xb;

  cvt_all<<<4096, 256, 0, stream>>>(x, w_qkv, w_out, xb, wqkvb, wob);
  gemm_bt<1><<<dim3(QKVN / 128, NROWS / 128), 256, 0, stream>>>(xb, wqkvb, qkvb, vtb, NROWS, QKVN, EMB);
  attn_causal18<<<1024, 256, 0, stream>>>(qkvb, vtb, yb);
  gemm_bt<0><<<dim3(EMB / 128, NROWS / 128), 256, 0, stream>>>(yb, wob, out, nullptr, NROWS, EMB, EMB);
}

// Round 20
// 90.707 us; speedup vs baseline: 1.2270x; 1.0815x over previous
//
#include <hip/hip_runtime.h>
#include <hip/hip_bf16.h>
#include <cstdint>

// ---------------------------------------------------------------------------
// Fused causal self-attention block (B=2, T=2048, C=1024, H=16, Dh=64), fp32 in/out.
// cvt fp32->bf16 -> QKV GEMM (Q pre-scaled, V written transposed) -> flash attn -> out GEMM.
// Workspace (48MB):
//   yb    @ 0     8 MB   bf16 x (xb) -> DEAD after gemm1 -> reused as yb
//   wqkvb @ 8 MB  6 MB   bf16 w_qkv [3072][1024]
//   wob   @ 14MB  2 MB   bf16 w_out [1024][1024]
//   qkvb  @ 16MB 24 MB   bf16 qkv [4096][3072] (Q scaled | K | V-region unused)
//   vt    @ 40MB  8 MB   bf16 Vt [32 bh][64 d][2048 t] (written by gemm1 epilogue)
// ---------------------------------------------------------------------------

typedef __bf16 bf16x8 __attribute__((ext_vector_type(8)));
typedef float  f32x4  __attribute__((ext_vector_type(4)));
typedef unsigned short u16x4 __attribute__((ext_vector_type(4)));
typedef unsigned int   u32x4 __attribute__((ext_vector_type(4)));

#define EMB   1024
#define HEADS 16
#define HD    64
#define TT    2048
#define NROWS 4096
#define QKVN  3072
#define SCL   0.18033688f   /* 0.125 * log2(e): folded into Q at gemm1 epilogue */
#define THR   11.0f         /* defer-max threshold, log2 units */

// ---- fused fp32 -> bf16 (8 elems / thread, 3 arrays in one launch) ----
__global__ void cvt_all(const float* __restrict__ x, const float* __restrict__ wq,
                        const float* __restrict__ wo, __bf16* __restrict__ xb,
                        __bf16* __restrict__ wqb, __bf16* __restrict__ wob) {
  const int bid = blockIdx.x;
  const float* in; __bf16* out; int i;
  if (bid < 2048)      { in = x;  out = xb;  i = bid * 256 + threadIdx.x; }
  else if (bid < 3584) { in = wq; out = wqb; i = (bid - 2048) * 256 + threadIdx.x; }
  else                 { in = wo; out = wob; i = (bid - 3584) * 256 + threadIdx.x; }
  const float4* p = (const float4*)in + (size_t)i * 2;
  float4 a = p[0], b = p[1];
  bf16x8 o;
  o[0] = (__bf16)a.x; o[1] = (__bf16)a.y; o[2] = (__bf16)a.z; o[3] = (__bf16)a.w;
  o[4] = (__bf16)b.x; o[5] = (__bf16)b.y; o[6] = (__bf16)b.z; o[7] = (__bf16)b.w;
  *((bf16x8*)out + i) = o;
}

__device__ __forceinline__ void gload_lds16(const void* g, void* l) {
  __builtin_amdgcn_global_load_lds(
      (const __attribute__((address_space(1))) void*)(uintptr_t)g,
      (__attribute__((address_space(3))) void*)(uint32_t)(uintptr_t)l,
      16, 0, 0);
}

// ---------------------------------------------------------------------------
// GEMM (R12): 128x128 tile, BK=64, chunk-swizzled staging, XCD swizzle.
// MODE 1 epilogue: Q scaled, K plain, V transposed to vt.
// ---------------------------------------------------------------------------
template <int MODE>
__global__ __launch_bounds__(256, 2)
void gemm_bt(const __bf16* __restrict__ A, const __bf16* __restrict__ Bm,
             void* __restrict__ Cout, __bf16* __restrict__ vt,
             int M, int N, int K) {
  __shared__ __align__(16) char As[128 * 128];
  __shared__ __align__(16) char Bs[128 * 128];
  const int tid  = threadIdx.x;
  const int lane = tid & 63;
  const int wid  = tid >> 6;
  const int wr = wid >> 1, wc = wid & 1;
  const int nwg = gridDim.x * gridDim.y;
  int flat = blockIdx.y * gridDim.x + blockIdx.x;
  flat = (flat & 7) * (nwg >> 3) + (flat >> 3);
  const int brow = (flat / gridDim.x) * 128;
  const int bcol = (flat % gridDim.x) * 128;
  const int fr = lane & 15, g = lane >> 4;

  f32x4 acc[4][4];
#pragma unroll
  for (int m = 0; m < 4; m++)
#pragma unroll
    for (int n = 0; n < 4; n++)
#pragma unroll
      for (int r = 0; r < 4; r++) acc[m][n][r] = 0.0f;

  for (int k0 = 0; k0 < K; k0 += 64) {
    __syncthreads();
#pragma unroll
    for (int i = 0; i < 4; i++) {
      const int c = tid + i * 256;
      const int row = c >> 3, pos = c & 7;
      const int sc = pos ^ (row & 7);
      gload_lds16(A  + (size_t)(brow + row) * K + k0 + sc * 8, As + c * 16);
      gload_lds16(Bm + (size_t)(bcol + row) * K + k0 + sc * 8, Bs + c * 16);
    }
    __syncthreads();

    bf16x8 af[4][2], bfr[4][2];
#pragma unroll
    for (int m = 0; m < 4; m++)
#pragma unroll
      for (int kc = 0; kc < 2; kc++) {
        const int row = wr * 64 + m * 16 + fr;
        af[m][kc] = *(const bf16x8*)(As + row * 128 + (((kc << 2) | g) ^ (fr & 7)) * 16);
      }
#pragma unroll
    for (int n = 0; n < 4; n++)
#pragma unroll
      for (int kc = 0; kc < 2; kc++) {
        const int row = wc * 64 + n * 16 + fr;
        bfr[n][kc] = *(const bf16x8*)(Bs + row * 128 + (((kc << 2) | g) ^ (fr & 7)) * 16);
      }
#pragma unroll
    for (int kc = 0; kc < 2; kc++)
#pragma unroll
      for (int m = 0; m < 4; m++)
#pragma unroll
        for (int n = 0; n < 4; n++)
          acc[m][n] = __builtin_amdgcn_mfma_f32_16x16x32_bf16(af[m][kc], bfr[n][kc], acc[m][n], 0, 0, 0);
  }

  const int rbase = brow + wr * 64 + g * 4;
  const int cbase = bcol + wc * 64 + fr;
  if (MODE == 0) {
#pragma unroll
    for (int m = 0; m < 4; m++)
#pragma unroll
      for (int n = 0; n < 4; n++) {
        const int col = cbase + n * 16;
#pragma unroll
        for (int r = 0; r < 4; r++)
          ((float*)Cout)[(size_t)(rbase + m * 16 + r) * N + col] = acc[m][n][r];
      }
  } else if (bcol < 2 * EMB) {
    const float qscale = (bcol < EMB) ? SCL : 1.0f;
#pragma unroll
    for (int m = 0; m < 4; m++)
#pragma unroll
      for (int n = 0; n < 4; n++) {
        const int col = cbase + n * 16;
#pragma unroll
        for (int r = 0; r < 4; r++)
          ((__bf16*)Cout)[(size_t)(rbase + m * 16 + r) * N + col] = (__bf16)(acc[m][n][r] * qscale);
      }
  } else {
#pragma unroll
    for (int m = 0; m < 4; m++) {
      const int row0 = rbase + m * 16;
      const int b = row0 >> 11, t0 = row0 & 2047;
#pragma unroll
      for (int n = 0; n < 4; n++) {
        const int vcol = cbase + n * 16 - 2 * EMB;
        const int bh = b * HEADS + (vcol >> 6);
        const int d  = vcol & 63;
        u16x4 pk;
#pragma unroll
        for (int r = 0; r < 4; r++) {
          const __bf16 h = (__bf16)acc[m][n][r];
          pk[r] = *(const unsigned short*)&h;
        }
        *(u16x4*)(vt + ((size_t)bh * HD + d) * TT + t0) = pk;
      }
    }
  }
}

// ---------------------------------------------------------------------------
// Causal flash attention v19 = v18 (swapped QK^T, VALU-pipe softmax, PASSED,
// 44.6us) + (a) v_cvt_pk_bf16_f32 P-packing (1 op/pair vs cast+or chain) and
// (b) 3-deep K/V buffers -> LDS 48KB -> 3 blocks/CU (12 waves/CU, +50%).
// 3-deep sync: buffers {t:PV, t+1:QK, t+2:stage}; stage(t+2) overwrites
// tile t-1's buffer (safe: all waves passed the iter-(t-1) barrier);
// end-of-iter vmcnt(0)+barrier forces this iter's stage landed (cheap: DMA
// had a full phase, K/V are L2-resident).  Routing/reductions on VALU pipe
// via permlane swaps with opaque-copy CSE guard (v18-verified).
// grid 1024 (32 chunks x 32 bh), LPT order.
// ---------------------------------------------------------------------------
__device__ __forceinline__ int psw(int row) {
  return (((row & 7) ^ ((row >> 3) & 7))) << 4;
}

__device__ __forceinline__ unsigned int pack_bf16(float a, float b) {
  unsigned int r;
  asm("v_cvt_pk_bf16_f32 %0, %1, %2" : "=v"(r) : "v"(a), "v"(b));
  return r;                                      // lo = bf16(a), hi = bf16(b)
}

__device__ __forceinline__ float opaque_f(float x) {
  float y;
  asm volatile("v_mov_b32 %0, %1" : "=v"(y) : "v"(x));
  return y;
}

__global__ __launch_bounds__(256, 3)
void attn_causal19(const __bf16* __restrict__ qkv, const __bf16* __restrict__ vt,
                   __bf16* __restrict__ yb) {
  __shared__ __align__(16) char Kbuf[3][8192];   // K[kv][d], chunk-swizzled
  __shared__ __align__(16) char Vbuf[3][8192];   // Vt[d][kv], chunk-swizzled

  const int tid = threadIdx.x;
  const int lane = tid & 63, w = tid >> 6;
  const int L = blockIdx.x;
  const int bh = L & 31;
  const int chunk = 31 - (L >> 5);               // LPT: longest first
  const int b = bh >> 4, h = bh & 15;
  const size_t rowbase = (size_t)b * TT;
  const int q0 = chunk * 64 + w * 16;
  const int fr = lane & 15, g = lane >> 4;
  const int ntiles = chunk + 1;

  bf16x8 qf[2];
#pragma unroll
  for (int kc = 0; kc < 2; kc++)
    qf[kc] = *(const bf16x8*)(qkv + (rowbase + q0 + fr) * QKVN + h * HD + kc * 32 + g * 8);

  f32x4 o[4];            // O^T frags: lane q=q0+fr holds d = n*16 + g*4 + r
  float lacc = 0.0f;     // row sum (scalar per lane)
  float ml = -1e30f;     // running max (scalar per lane)
#pragma unroll
  for (int n = 0; n < 4; n++)
#pragma unroll
    for (int r = 0; r < 4; r++) o[n][r] = 0.0f;

  auto stageKV = [&](int kt, int buf) {
#pragma unroll
    for (int i = 0; i < 2; i++) {
      const int c = tid + i * 256;
      const int row = c >> 3;
      const int c16 = (c & 7) ^ (row & 7);
      gload_lds16(qkv + (rowbase + kt * 64 + row) * QKVN + EMB + h * HD + c16 * 8,
                  Kbuf[buf] + c * 16);
    }
#pragma unroll
    for (int i = 0; i < 2; i++) {
      const int c = tid + i * 256;
      const int row = c >> 3;
      const int c16 = (c & 7) ^ (row & 7);
      gload_lds16(vt + ((size_t)bh * HD + row) * TT + kt * 64 + c16 * 8,
                  Vbuf[buf] + c * 16);
    }
  };

  // S^T = mfma(A=K, B=Q): s[n][r] = S[q=q0+fr][kv = kt*64 + n*16 + g*4 + r]
  auto doQK = [&](int kt, f32x4 (&s)[4]) {
    const char* Kc = Kbuf[kt % 3];
    bf16x8 kf[4][2];
#pragma unroll
    for (int n = 0; n < 4; n++)
#pragma unroll
      for (int kc = 0; kc < 2; kc++) {
        const int row = n * 16 + fr;
        kf[n][kc] = *(const bf16x8*)(Kc + row * 128 + (((kc << 2) | g) ^ (row & 7)) * 16);
      }
    __builtin_amdgcn_s_setprio(1);
#pragma unroll
    for (int n = 0; n < 4; n++) {
#pragma unroll
      for (int r = 0; r < 4; r++) s[n][r] = 0.0f;
#pragma unroll
      for (int kc = 0; kc < 2; kc++)
        s[n] = __builtin_amdgcn_mfma_f32_16x16x32_bf16(kf[n][kc], qf[kc], s[n], 0, 0, 0);
    }
    __builtin_amdgcn_s_setprio(0);
  };

  // in-register softmax + P^T B-operand assembly via permlane swaps (VALU)
  auto doSM = [&](int kt, f32x4 (&s)[4], bf16x8 (&pb)[2]) {
    const int kv0 = kt * 64;
    if (kt == chunk) {                           // causal mask, diagonal tile
      const int qg = q0 + fr;
#pragma unroll
      for (int n = 0; n < 4; n++)
#pragma unroll
        for (int r = 0; r < 4; r++) {
          const int kg = kv0 + n * 16 + g * 4 + r;
          if (kg > qg) s[n][r] = -1e30f;
        }
    }
    float pm = s[0][0];
#pragma unroll
    for (int n = 0; n < 4; n++)
#pragma unroll
      for (int r = 0; r < 4; r++) pm = fmaxf(pm, s[n][r]);
    {
      float c16 = opaque_f(pm);
      asm("v_permlane16_swap_b32 %0, %1" : "+v"(pm), "+v"(c16));
      pm = fmaxf(pm, c16);
      float c32 = opaque_f(pm);
      asm("v_permlane32_swap_b32 %0, %1" : "+v"(pm), "+v"(c32));
      pm = fmaxf(pm, c32);
    }
    if (!__all(pm <= ml + THR)) {
      const float nm = fmaxf(ml, pm);
      const float f = __builtin_amdgcn_exp2f(ml - nm);
      ml = nm;
      lacc *= f;
#pragma unroll
      for (int n = 0; n < 4; n++)
#pragma unroll
        for (int r = 0; r < 4; r++) o[n][r] *= f;
    }
    float p[4][4];
    float ts = 0.0f;
#pragma unroll
    for (int n = 0; n < 4; n++)
#pragma unroll
      for (int r = 0; r < 4; r++) {
        p[n][r] = __builtin_amdgcn_exp2f(s[n][r] - ml);
        ts += p[n][r];
      }
    {
      float c16 = opaque_f(ts);
      asm("v_permlane16_swap_b32 %0, %1" : "+v"(ts), "+v"(c16));
      ts = ts + c16;
      float c32 = opaque_f(ts);
      asm("v_permlane32_swap_b32 %0, %1" : "+v"(ts), "+v"(c32));
      ts = ts + c32;
    }
    lacc += ts;
    // pack adjacent-kv pairs with v_cvt_pk_bf16_f32 (T12 recipe)
    unsigned int pk[4][2];
#pragma unroll
    for (int n = 0; n < 4; n++)
#pragma unroll
      for (int w2 = 0; w2 < 2; w2++)
        pk[n][w2] = pack_bf16(p[n][2 * w2], p[n][2 * w2 + 1]);
    // route to B-frag via permlane swaps (distinct inputs -> no CSE hazard)
#pragma unroll
    for (int kc = 0; kc < 2; kc++) {
      unsigned int a0 = pk[2 * kc][0], b0 = pk[2 * kc + 1][0];
      asm("v_permlane32_swap_b32 %0, %1" : "+v"(a0), "+v"(b0));
      asm("v_permlane16_swap_b32 %0, %1" : "+v"(a0), "+v"(b0));
      unsigned int a1 = pk[2 * kc][1], b1 = pk[2 * kc + 1][1];
      asm("v_permlane32_swap_b32 %0, %1" : "+v"(a1), "+v"(b1));
      asm("v_permlane16_swap_b32 %0, %1" : "+v"(a1), "+v"(b1));
      u32x4 bw;
      bw[0] = a0; bw[1] = a1; bw[2] = b0; bw[3] = b1;
      pb[kc] = *(bf16x8*)&bw;
    }
  };

  // O^T += mfma(A=Vt frag, B=P^T)
  auto doPV = [&](int kt, bf16x8 (&pb)[2]) {
    const char* Vc = Vbuf[kt % 3];
    bf16x8 vb[4][2];
#pragma unroll
    for (int n = 0; n < 4; n++)
#pragma unroll
      for (int kc = 0; kc < 2; kc++) {
        const int row = n * 16 + fr;
        vb[n][kc] = *(const bf16x8*)(Vc + row * 128 + (((kc << 2) | g) ^ (row & 7)) * 16);
      }
    __builtin_amdgcn_s_setprio(1);
#pragma unroll
    for (int kc = 0; kc < 2; kc++)
#pragma unroll
      for (int n = 0; n < 4; n++)
        o[n] = __builtin_amdgcn_mfma_f32_16x16x32_bf16(vb[n][kc], pb[kc], o[n], 0, 0, 0);
    __builtin_amdgcn_s_setprio(0);
  };

  // ---- prologue: stage tiles 0,1; drain; tile-0 QK+SM ----
  stageKV(0, 0);
  if (ntiles > 1) stageKV(1, 1);
  asm volatile("s_waitcnt vmcnt(0)" ::: "memory");
  __builtin_amdgcn_s_barrier();

  bf16x8 pb[2];
  {
    f32x4 s0[4];
    doQK(0, s0);
    doSM(0, s0, pb);
  }

  for (int t = 0; t < ntiles; t++) {
    if (t + 2 < ntiles) stageKV(t + 2, (t + 2) % 3);

    const bool nxt = (t + 1 < ntiles);
    f32x4 s[4];
    if (nxt) doQK(t + 1, s);          // overlaps PV(t)
    doPV(t, pb);                      // consumes pb(t)
    if (nxt) doSM(t + 1, s, pb);      // rescale o AFTER PV(t); makes pb(t+1)

    asm volatile("s_waitcnt vmcnt(0)" ::: "memory");   // this iter's stage landed
    __builtin_amdgcn_s_barrier();
  }

  // ---- epilogue: O^T -> [q][d] via per-wave LDS region (Kbuf dead) ----
  {
    char* Tw = (char*)Kbuf + w * 2048;           // [16 q][64 d] bf16, psw-swizzled
    const float inv = __builtin_amdgcn_rcpf(lacc);
#pragma unroll
    for (int n = 0; n < 4; n++)
#pragma unroll
      for (int r = 0; r < 4; r++) {
        const int d = n * 16 + g * 4 + r;
        *(__bf16*)(Tw + fr * 128 + ((d * 2) ^ psw(fr))) = (__bf16)(o[n][r] * inv);
      }
#pragma unroll
    for (int i = 0; i < 2; i++) {
      const int c = lane + i * 64;               // 128 16B-chunks
      const int row = c >> 3, pos = c & 7;
      const bf16x8 v = *(const bf16x8*)(Tw + row * 128 + ((pos * 16) ^ psw(row)));
      *(bf16x8*)(yb + (rowbase + q0 + row) * EMB + h * HD + pos * 8) = v;
    }
  }
}

extern "C" void kernel_launch(void* const* d_in, const int* in_sizes, int n_in,
                              void* d_out, int out_size, void* d_ws, size_t ws_size,
                              hipStream_t stream) {
  const float* x     = (const float*)d_in[0];
  const float* w_qkv = (const float*)d_in[1];
  const float* w_out = (const float*)d_in[2];
  float* out = (float*)d_out;

  char* ws = (char*)d_ws;
  __bf16* xb    = (__bf16*)(ws);                 // dead after gemm1 -> reused as yb
  __bf16* wqkvb = (__bf16*)(ws + (8ull  << 20));
  __bf16* wob   = (__bf16*)(ws + (14ull << 20));
  __bf16* qkvb  = (__bf16*)(ws + (16ull << 20));
  __bf16* vtb   = (__bf16*)(ws + (40ull << 20));
  __bf16* yb    = xb;

  cvt_all<<<4096, 256, 0, stream>>>(x, w_qkv, w_out, xb, wqkvb, wob);
  gemm_bt<1><<<dim3(QKVN / 128, NROWS / 128), 256, 0, stream>>>(xb, wqkvb, qkvb, vtb, NROWS, QKVN, EMB);
  attn_causal19<<<1024, 256, 0, stream>>>(qkvb, vtb, yb);
  gemm_bt<0><<<dim3(EMB / 128, NROWS / 128), 256, 0, stream>>>(yb, wob, out, nullptr, NROWS, EMB, EMB);
}

// Round 21
// 88.907 us; speedup vs baseline: 1.2519x; 1.0203x over previous
//
#include <hip/hip_runtime.h>
#include <hip/hip_bf16.h>
#include <cstdint>

// ---------------------------------------------------------------------------
// Fused causal self-attention block (B=2, T=2048, C=1024, H=16, Dh=64), fp32 in/out.
// cvt fp32->bf16 -> QKV GEMM (Q pre-scaled, V written transposed) -> flash attn -> out GEMM.
// Workspace (48MB):
//   yb    @ 0     8 MB   bf16 x (xb) -> DEAD after gemm1 -> reused as yb
//   wqkvb @ 8 MB  6 MB   bf16 w_qkv [3072][1024]
//   wob   @ 14MB  2 MB   bf16 w_out [1024][1024]
//   qkvb  @ 16MB 24 MB   bf16 qkv [4096][3072] (Q scaled | K | V-region unused)
//   vt    @ 40MB  8 MB   bf16 Vt [32 bh][64 d][2048 t] (written by gemm1 epilogue)
// ---------------------------------------------------------------------------

typedef __bf16 bf16x8 __attribute__((ext_vector_type(8)));
typedef float  f32x4  __attribute__((ext_vector_type(4)));
typedef unsigned short u16x4 __attribute__((ext_vector_type(4)));
typedef unsigned int   u32x4 __attribute__((ext_vector_type(4)));

#define EMB   1024
#define HEADS 16
#define HD    64
#define TT    2048
#define NROWS 4096
#define QKVN  3072
#define SCL   0.18033688f   /* 0.125 * log2(e): folded into Q at gemm1 epilogue */
#define THR   11.0f         /* defer-max threshold, log2 units */

// ---- fused fp32 -> bf16 (8 elems / thread, 3 arrays in one launch) ----
__global__ void cvt_all(const float* __restrict__ x, const float* __restrict__ wq,
                        const float* __restrict__ wo, __bf16* __restrict__ xb,
                        __bf16* __restrict__ wqb, __bf16* __restrict__ wob) {
  const int bid = blockIdx.x;
  const float* in; __bf16* out; int i;
  if (bid < 2048)      { in = x;  out = xb;  i = bid * 256 + threadIdx.x; }
  else if (bid < 3584) { in = wq; out = wqb; i = (bid - 2048) * 256 + threadIdx.x; }
  else                 { in = wo; out = wob; i = (bid - 3584) * 256 + threadIdx.x; }
  const float4* p = (const float4*)in + (size_t)i * 2;
  float4 a = p[0], b = p[1];
  bf16x8 o;
  o[0] = (__bf16)a.x; o[1] = (__bf16)a.y; o[2] = (__bf16)a.z; o[3] = (__bf16)a.w;
  o[4] = (__bf16)b.x; o[5] = (__bf16)b.y; o[6] = (__bf16)b.z; o[7] = (__bf16)b.w;
  *((bf16x8*)out + i) = o;
}

__device__ __forceinline__ void gload_lds16(const void* g, void* l) {
  __builtin_amdgcn_global_load_lds(
      (const __attribute__((address_space(1))) void*)(uintptr_t)g,
      (__attribute__((address_space(3))) void*)(uint32_t)(uintptr_t)l,
      16, 0, 0);
}

// ---------------------------------------------------------------------------
// GEMM (R12): 128x128 tile, BK=64, chunk-swizzled staging, XCD swizzle.
// MODE 1 epilogue: Q scaled, K plain, V transposed to vt.
// ---------------------------------------------------------------------------
template <int MODE>
__global__ __launch_bounds__(256, 2)
void gemm_bt(const __bf16* __restrict__ A, const __bf16* __restrict__ Bm,
             void* __restrict__ Cout, __bf16* __restrict__ vt,
             int M, int N, int K) {
  __shared__ __align__(16) char As[128 * 128];
  __shared__ __align__(16) char Bs[128 * 128];
  const int tid  = threadIdx.x;
  const int lane = tid & 63;
  const int wid  = tid >> 6;
  const int wr = wid >> 1, wc = wid & 1;
  const int nwg = gridDim.x * gridDim.y;
  int flat = blockIdx.y * gridDim.x + blockIdx.x;
  flat = (flat & 7) * (nwg >> 3) + (flat >> 3);
  const int brow = (flat / gridDim.x) * 128;
  const int bcol = (flat % gridDim.x) * 128;
  const int fr = lane & 15, g = lane >> 4;

  f32x4 acc[4][4];
#pragma unroll
  for (int m = 0; m < 4; m++)
#pragma unroll
    for (int n = 0; n < 4; n++)
#pragma unroll
      for (int r = 0; r < 4; r++) acc[m][n][r] = 0.0f;

  for (int k0 = 0; k0 < K; k0 += 64) {
    __syncthreads();
#pragma unroll
    for (int i = 0; i < 4; i++) {
      const int c = tid + i * 256;
      const int row = c >> 3, pos = c & 7;
      const int sc = pos ^ (row & 7);
      gload_lds16(A  + (size_t)(brow + row) * K + k0 + sc * 8, As + c * 16);
      gload_lds16(Bm + (size_t)(bcol + row) * K + k0 + sc * 8, Bs + c * 16);
    }
    __syncthreads();

    bf16x8 af[4][2], bfr[4][2];
#pragma unroll
    for (int m = 0; m < 4; m++)
#pragma unroll
      for (int kc = 0; kc < 2; kc++) {
        const int row = wr * 64 + m * 16 + fr;
        af[m][kc] = *(const bf16x8*)(As + row * 128 + (((kc << 2) | g) ^ (fr & 7)) * 16);
      }
#pragma unroll
    for (int n = 0; n < 4; n++)
#pragma unroll
      for (int kc = 0; kc < 2; kc++) {
        const int row = wc * 64 + n * 16 + fr;
        bfr[n][kc] = *(const bf16x8*)(Bs + row * 128 + (((kc << 2) | g) ^ (fr & 7)) * 16);
      }
#pragma unroll
    for (int kc = 0; kc < 2; kc++)
#pragma unroll
      for (int m = 0; m < 4; m++)
#pragma unroll
        for (int n = 0; n < 4; n++)
          acc[m][n] = __builtin_amdgcn_mfma_f32_16x16x32_bf16(af[m][kc], bfr[n][kc], acc[m][n], 0, 0, 0);
  }

  const int rbase = brow + wr * 64 + g * 4;
  const int cbase = bcol + wc * 64 + fr;
  if (MODE == 0) {
#pragma unroll
    for (int m = 0; m < 4; m++)
#pragma unroll
      for (int n = 0; n < 4; n++) {
        const int col = cbase + n * 16;
#pragma unroll
        for (int r = 0; r < 4; r++)
          ((float*)Cout)[(size_t)(rbase + m * 16 + r) * N + col] = acc[m][n][r];
      }
  } else if (bcol < 2 * EMB) {
    const float qscale = (bcol < EMB) ? SCL : 1.0f;
#pragma unroll
    for (int m = 0; m < 4; m++)
#pragma unroll
      for (int n = 0; n < 4; n++) {
        const int col = cbase + n * 16;
#pragma unroll
        for (int r = 0; r < 4; r++)
          ((__bf16*)Cout)[(size_t)(rbase + m * 16 + r) * N + col] = (__bf16)(acc[m][n][r] * qscale);
      }
  } else {
#pragma unroll
    for (int m = 0; m < 4; m++) {
      const int row0 = rbase + m * 16;
      const int b = row0 >> 11, t0 = row0 & 2047;
#pragma unroll
      for (int n = 0; n < 4; n++) {
        const int vcol = cbase + n * 16 - 2 * EMB;
        const int bh = b * HEADS + (vcol >> 6);
        const int d  = vcol & 63;
        u16x4 pk;
#pragma unroll
        for (int r = 0; r < 4; r++) {
          const __bf16 h = (__bf16)acc[m][n][r];
          pk[r] = *(const unsigned short*)&h;
        }
        *(u16x4*)(vt + ((size_t)bh * HD + d) * TT + t0) = pk;
      }
    }
  }
}

// ---------------------------------------------------------------------------
// Causal flash attention v20 = v19 (swapped QK^T, VALU softmax, 3-deep, 3
// blocks/CU, PASSED) + row-sum moved to the MFMA pipe: with A=ones,
// D[row][col] = sum_k P^T[k][col] = l_{q=col} -> every lane's 4 regs hold
// l_{q=fr} replicated; accumulate f32x4 across tiles, rescale with f, take
// [0] at the end.  Removes 16 add + 2 permlane + 2 mov VALU per tile for
// 2 MFMA.  Also: final iteration skips the drain+barrier (epilogue is
// wave-private).  grid 1024 (32 chunks x 32 bh), LPT.  LDS 48KB.
// ---------------------------------------------------------------------------
__device__ __forceinline__ int psw(int row) {
  return (((row & 7) ^ ((row >> 3) & 7))) << 4;
}

__device__ __forceinline__ unsigned int pack_bf16(float a, float b) {
  unsigned int r;
  asm("v_cvt_pk_bf16_f32 %0, %1, %2" : "=v"(r) : "v"(a), "v"(b));
  return r;                                      // lo = bf16(a), hi = bf16(b)
}

__device__ __forceinline__ float opaque_f(float x) {
  float y;
  asm volatile("v_mov_b32 %0, %1" : "=v"(y) : "v"(x));
  return y;
}

__global__ __launch_bounds__(256, 3)
void attn_causal20(const __bf16* __restrict__ qkv, const __bf16* __restrict__ vt,
                   __bf16* __restrict__ yb) {
  __shared__ __align__(16) char Kbuf[3][8192];   // K[kv][d], chunk-swizzled
  __shared__ __align__(16) char Vbuf[3][8192];   // Vt[d][kv], chunk-swizzled

  const int tid = threadIdx.x;
  const int lane = tid & 63, w = tid >> 6;
  const int L = blockIdx.x;
  const int bh = L & 31;
  const int chunk = 31 - (L >> 5);               // LPT: longest first
  const int b = bh >> 4, h = bh & 15;
  const size_t rowbase = (size_t)b * TT;
  const int q0 = chunk * 64 + w * 16;
  const int fr = lane & 15, g = lane >> 4;
  const int ntiles = chunk + 1;

  bf16x8 qf[2];
#pragma unroll
  for (int kc = 0; kc < 2; kc++)
    qf[kc] = *(const bf16x8*)(qkv + (rowbase + q0 + fr) * QKVN + h * HD + kc * 32 + g * 8);

  bf16x8 ones;
#pragma unroll
  for (int j = 0; j < 8; j++) ones[j] = (__bf16)1.0f;

  f32x4 o[4];            // O^T frags: lane q=q0+fr holds d = n*16 + g*4 + r
  f32x4 lacc;            // ones-MFMA row-sum: all 4 regs = l_{q=fr}
  float ml = -1e30f;     // running max (scalar per lane)
#pragma unroll
  for (int n = 0; n < 4; n++)
#pragma unroll
    for (int r = 0; r < 4; r++) o[n][r] = 0.0f;
#pragma unroll
  for (int r = 0; r < 4; r++) lacc[r] = 0.0f;

  auto stageKV = [&](int kt, int buf) {
#pragma unroll
    for (int i = 0; i < 2; i++) {
      const int c = tid + i * 256;
      const int row = c >> 3;
      const int c16 = (c & 7) ^ (row & 7);
      gload_lds16(qkv + (rowbase + kt * 64 + row) * QKVN + EMB + h * HD + c16 * 8,
                  Kbuf[buf] + c * 16);
    }
#pragma unroll
    for (int i = 0; i < 2; i++) {
      const int c = tid + i * 256;
      const int row = c >> 3;
      const int c16 = (c & 7) ^ (row & 7);
      gload_lds16(vt + ((size_t)bh * HD + row) * TT + kt * 64 + c16 * 8,
                  Vbuf[buf] + c * 16);
    }
  };

  // S^T = mfma(A=K, B=Q): s[n][r] = S[q=q0+fr][kv = kt*64 + n*16 + g*4 + r]
  auto doQK = [&](int kt, f32x4 (&s)[4]) {
    const char* Kc = Kbuf[kt % 3];
    bf16x8 kf[4][2];
#pragma unroll
    for (int n = 0; n < 4; n++)
#pragma unroll
      for (int kc = 0; kc < 2; kc++) {
        const int row = n * 16 + fr;
        kf[n][kc] = *(const bf16x8*)(Kc + row * 128 + (((kc << 2) | g) ^ (row & 7)) * 16);
      }
    __builtin_amdgcn_s_setprio(1);
#pragma unroll
    for (int n = 0; n < 4; n++) {
#pragma unroll
      for (int r = 0; r < 4; r++) s[n][r] = 0.0f;
#pragma unroll
      for (int kc = 0; kc < 2; kc++)
        s[n] = __builtin_amdgcn_mfma_f32_16x16x32_bf16(kf[n][kc], qf[kc], s[n], 0, 0, 0);
    }
    __builtin_amdgcn_s_setprio(0);
  };

  // in-register softmax + P^T B-operand assembly via permlane swaps (VALU)
  auto doSM = [&](int kt, f32x4 (&s)[4], bf16x8 (&pb)[2]) {
    const int kv0 = kt * 64;
    if (kt == chunk) {                           // causal mask, diagonal tile
      const int qg = q0 + fr;
#pragma unroll
      for (int n = 0; n < 4; n++)
#pragma unroll
        for (int r = 0; r < 4; r++) {
          const int kg = kv0 + n * 16 + g * 4 + r;
          if (kg > qg) s[n][r] = -1e30f;
        }
    }
    float pm = s[0][0];
#pragma unroll
    for (int n = 0; n < 4; n++)
#pragma unroll
      for (int r = 0; r < 4; r++) pm = fmaxf(pm, s[n][r]);
    {
      float c16 = opaque_f(pm);
      asm("v_permlane16_swap_b32 %0, %1" : "+v"(pm), "+v"(c16));
      pm = fmaxf(pm, c16);
      float c32 = opaque_f(pm);
      asm("v_permlane32_swap_b32 %0, %1" : "+v"(pm), "+v"(c32));
      pm = fmaxf(pm, c32);
    }
    if (!__all(pm <= ml + THR)) {
      const float nm = fmaxf(ml, pm);
      const float f = __builtin_amdgcn_exp2f(ml - nm);
      ml = nm;
#pragma unroll
      for (int r = 0; r < 4; r++) lacc[r] *= f;
#pragma unroll
      for (int n = 0; n < 4; n++)
#pragma unroll
        for (int r = 0; r < 4; r++) o[n][r] *= f;
    }
    float p[4][4];
#pragma unroll
    for (int n = 0; n < 4; n++)
#pragma unroll
      for (int r = 0; r < 4; r++)
        p[n][r] = __builtin_amdgcn_exp2f(s[n][r] - ml);
    // pack adjacent-kv pairs with v_cvt_pk_bf16_f32 (T12 recipe)
    unsigned int pk[4][2];
#pragma unroll
    for (int n = 0; n < 4; n++)
#pragma unroll
      for (int w2 = 0; w2 < 2; w2++)
        pk[n][w2] = pack_bf16(p[n][2 * w2], p[n][2 * w2 + 1]);
    // route to B-frag via permlane swaps (distinct inputs -> no CSE hazard)
#pragma unroll
    for (int kc = 0; kc < 2; kc++) {
      unsigned int a0 = pk[2 * kc][0], b0 = pk[2 * kc + 1][0];
      asm("v_permlane32_swap_b32 %0, %1" : "+v"(a0), "+v"(b0));
      asm("v_permlane16_swap_b32 %0, %1" : "+v"(a0), "+v"(b0));
      unsigned int a1 = pk[2 * kc][1], b1 = pk[2 * kc + 1][1];
      asm("v_permlane32_swap_b32 %0, %1" : "+v"(a1), "+v"(b1));
      asm("v_permlane16_swap_b32 %0, %1" : "+v"(a1), "+v"(b1));
      u32x4 bw;
      bw[0] = a0; bw[1] = a1; bw[2] = b0; bw[3] = b1;
      pb[kc] = *(bf16x8*)&bw;
    }
  };

  // O^T += mfma(A=Vt frag, B=P^T); lacc += mfma(A=ones, B=P^T)
  auto doPV = [&](int kt, bf16x8 (&pb)[2]) {
    const char* Vc = Vbuf[kt % 3];
    bf16x8 vb[4][2];
#pragma unroll
    for (int n = 0; n < 4; n++)
#pragma unroll
      for (int kc = 0; kc < 2; kc++) {
        const int row = n * 16 + fr;
        vb[n][kc] = *(const bf16x8*)(Vc + row * 128 + (((kc << 2) | g) ^ (row & 7)) * 16);
      }
    __builtin_amdgcn_s_setprio(1);
#pragma unroll
    for (int kc = 0; kc < 2; kc++) {
      lacc = __builtin_amdgcn_mfma_f32_16x16x32_bf16(ones, pb[kc], lacc, 0, 0, 0);
#pragma unroll
      for (int n = 0; n < 4; n++)
        o[n] = __builtin_amdgcn_mfma_f32_16x16x32_bf16(vb[n][kc], pb[kc], o[n], 0, 0, 0);
    }
    __builtin_amdgcn_s_setprio(0);
  };

  // ---- prologue: stage tiles 0,1; drain; tile-0 QK+SM ----
  stageKV(0, 0);
  if (ntiles > 1) stageKV(1, 1);
  asm volatile("s_waitcnt vmcnt(0)" ::: "memory");
  __builtin_amdgcn_s_barrier();

  bf16x8 pb[2];
  {
    f32x4 s0[4];
    doQK(0, s0);
    doSM(0, s0, pb);
  }

  for (int t = 0; t < ntiles; t++) {
    if (t + 2 < ntiles) stageKV(t + 2, (t + 2) % 3);

    const bool nxt = (t + 1 < ntiles);
    f32x4 s[4];
    if (nxt) doQK(t + 1, s);          // overlaps PV(t)
    doPV(t, pb);                      // consumes pb(t)
    if (nxt) doSM(t + 1, s, pb);      // rescale o AFTER PV(t); makes pb(t+1)

    if (nxt) {                        // final iteration: no drain, no barrier
      asm volatile("s_waitcnt vmcnt(0)" ::: "memory");
      __builtin_amdgcn_s_barrier();
    }
  }

  // ---- epilogue: O^T -> [q][d] via per-wave LDS region (Kbuf dead) ----
  {
    char* Tw = (char*)Kbuf + w * 2048;           // [16 q][64 d] bf16, psw-swizzled
    const float inv = __builtin_amdgcn_rcpf(lacc[0]);
#pragma unroll
    for (int n = 0; n < 4; n++)
#pragma unroll
      for (int r = 0; r < 4; r++) {
        const int d = n * 16 + g * 4 + r;
        *(__bf16*)(Tw + fr * 128 + ((d * 2) ^ psw(fr))) = (__bf16)(o[n][r] * inv);
      }
#pragma unroll
    for (int i = 0; i < 2; i++) {
      const int c = lane + i * 64;               // 128 16B-chunks
      const int row = c >> 3, pos = c & 7;
      const bf16x8 v = *(const bf16x8*)(Tw + row * 128 + ((pos * 16) ^ psw(row)));
      *(bf16x8*)(yb + (rowbase + q0 + row) * EMB + h * HD + pos * 8) = v;
    }
  }
}

extern "C" void kernel_launch(void* const* d_in, const int* in_sizes, int n_in,
                              void* d_out, int out_size, void* d_ws, size_t ws_size,
                              hipStream_t stream) {
  const float* x     = (const float*)d_in[0];
  const float* w_qkv = (const float*)d_in[1];
  const float* w_out = (const float*)d_in[2];
  float* out = (float*)d_out;

  char* ws = (char*)d_ws;
  __bf16* xb    = (__bf16*)(ws);                 // dead after gemm1 -> reused as yb
  __bf16* wqkvb = (__bf16*)(ws + (8ull  << 20));
  __bf16* wob   = (__bf16*)(ws + (14ull << 20));
  __bf16* qkvb  = (__bf16*)(ws + (16ull << 20));
  __bf16* vtb   = (__bf16*)(ws + (40ull << 20));
  __bf16* yb    = xb;

  cvt_all<<<4096, 256, 0, stream>>>(x, w_qkv, w_out, xb, wqkvb, wob);
  gemm_bt<1><<<dim3(QKVN / 128, NROWS / 128), 256, 0, stream>>>(xb, wqkvb, qkvb, vtb, NROWS, QKVN, EMB);
  attn_causal20<<<1024, 256, 0, stream>>>(qkvb, vtb, yb);
  gemm_bt<0><<<dim3(EMB / 128, NROWS / 128), 256, 0, stream>>>(yb, wob, out, nullptr, NROWS, EMB, EMB);
}

// Round 22
// 88.829 us; speedup vs baseline: 1.2530x; 1.0009x over previous
//
#include <hip/hip_runtime.h>
#include <hip/hip_bf16.h>
#include <cstdint>

// ---------------------------------------------------------------------------
// Fused causal self-attention block (B=2, T=2048, C=1024, H=16, Dh=64), fp32 in/out.
// cvt fp32->bf16 -> QKV GEMM (Q pre-scaled, V written transposed) -> flash attn -> out GEMM.
// Workspace (48MB):
//   yb    @ 0     8 MB   bf16 x (xb) -> DEAD after gemm1 -> reused as yb
//   wqkvb @ 8 MB  6 MB   bf16 w_qkv [3072][1024]
//   wob   @ 14MB  2 MB   bf16 w_out [1024][1024]
//   qkvb  @ 16MB 24 MB   bf16 qkv [4096][3072] (Q scaled | K | V-region unused)
//   vt    @ 40MB  8 MB   bf16 Vt [32 bh][64 d][2048 t] (written by gemm1 epilogue)
// ---------------------------------------------------------------------------

typedef __bf16 bf16x8 __attribute__((ext_vector_type(8)));
typedef float  f32x4  __attribute__((ext_vector_type(4)));
typedef unsigned short u16x4 __attribute__((ext_vector_type(4)));
typedef unsigned int   u32x4 __attribute__((ext_vector_type(4)));

#define EMB   1024
#define HEADS 16
#define HD    64
#define TT    2048
#define NROWS 4096
#define QKVN  3072
#define SCL   0.18033688f   /* 0.125 * log2(e): folded into Q at gemm1 epilogue */
#define THR   11.0f         /* defer-max threshold, log2 units */

// ---- fused fp32 -> bf16 (8 elems / thread, 3 arrays in one launch) ----
__global__ void cvt_all(const float* __restrict__ x, const float* __restrict__ wq,
                        const float* __restrict__ wo, __bf16* __restrict__ xb,
                        __bf16* __restrict__ wqb, __bf16* __restrict__ wob) {
  const int bid = blockIdx.x;
  const float* in; __bf16* out; int i;
  if (bid < 2048)      { in = x;  out = xb;  i = bid * 256 + threadIdx.x; }
  else if (bid < 3584) { in = wq; out = wqb; i = (bid - 2048) * 256 + threadIdx.x; }
  else                 { in = wo; out = wob; i = (bid - 3584) * 256 + threadIdx.x; }
  const float4* p = (const float4*)in + (size_t)i * 2;
  float4 a = p[0], b = p[1];
  bf16x8 o;
  o[0] = (__bf16)a.x; o[1] = (__bf16)a.y; o[2] = (__bf16)a.z; o[3] = (__bf16)a.w;
  o[4] = (__bf16)b.x; o[5] = (__bf16)b.y; o[6] = (__bf16)b.z; o[7] = (__bf16)b.w;
  *((bf16x8*)out + i) = o;
}

__device__ __forceinline__ void gload_lds16(const void* g, void* l) {
  __builtin_amdgcn_global_load_lds(
      (const __attribute__((address_space(1))) void*)(uintptr_t)g,
      (__attribute__((address_space(3))) void*)(uint32_t)(uintptr_t)l,
      16, 0, 0);
}

// ---------------------------------------------------------------------------
// GEMM (R12 + occupancy bump): 128x128 tile, BK=64, chunk-swizzled staging,
// XCD swizzle.  __launch_bounds__(256,3) -> 3 blocks/CU (was 2): +50% waves
// to hide the per-K-step staging drain.  MODE 1 epilogue: Q scaled, K plain,
// V transposed to vt.
// ---------------------------------------------------------------------------
template <int MODE>
__global__ __launch_bounds__(256, 3)
void gemm_bt(const __bf16* __restrict__ A, const __bf16* __restrict__ Bm,
             void* __restrict__ Cout, __bf16* __restrict__ vt,
             int M, int N, int K) {
  __shared__ __align__(16) char As[128 * 128];
  __shared__ __align__(16) char Bs[128 * 128];
  const int tid  = threadIdx.x;
  const int lane = tid & 63;
  const int wid  = tid >> 6;
  const int wr = wid >> 1, wc = wid & 1;
  const int nwg = gridDim.x * gridDim.y;
  int flat = blockIdx.y * gridDim.x + blockIdx.x;
  flat = (flat & 7) * (nwg >> 3) + (flat >> 3);
  const int brow = (flat / gridDim.x) * 128;
  const int bcol = (flat % gridDim.x) * 128;
  const int fr = lane & 15, g = lane >> 4;

  f32x4 acc[4][4];
#pragma unroll
  for (int m = 0; m < 4; m++)
#pragma unroll
    for (int n = 0; n < 4; n++)
#pragma unroll
      for (int r = 0; r < 4; r++) acc[m][n][r] = 0.0f;

  for (int k0 = 0; k0 < K; k0 += 64) {
    __syncthreads();
#pragma unroll
    for (int i = 0; i < 4; i++) {
      const int c = tid + i * 256;
      const int row = c >> 3, pos = c & 7;
      const int sc = pos ^ (row & 7);
      gload_lds16(A  + (size_t)(brow + row) * K + k0 + sc * 8, As + c * 16);
      gload_lds16(Bm + (size_t)(bcol + row) * K + k0 + sc * 8, Bs + c * 16);
    }
    __syncthreads();

    bf16x8 af[4][2], bfr[4][2];
#pragma unroll
    for (int m = 0; m < 4; m++)
#pragma unroll
      for (int kc = 0; kc < 2; kc++) {
        const int row = wr * 64 + m * 16 + fr;
        af[m][kc] = *(const bf16x8*)(As + row * 128 + (((kc << 2) | g) ^ (fr & 7)) * 16);
      }
#pragma unroll
    for (int n = 0; n < 4; n++)
#pragma unroll
      for (int kc = 0; kc < 2; kc++) {
        const int row = wc * 64 + n * 16 + fr;
        bfr[n][kc] = *(const bf16x8*)(Bs + row * 128 + (((kc << 2) | g) ^ (fr & 7)) * 16);
      }
#pragma unroll
    for (int kc = 0; kc < 2; kc++)
#pragma unroll
      for (int m = 0; m < 4; m++)
#pragma unroll
        for (int n = 0; n < 4; n++)
          acc[m][n] = __builtin_amdgcn_mfma_f32_16x16x32_bf16(af[m][kc], bfr[n][kc], acc[m][n], 0, 0, 0);
  }

  const int rbase = brow + wr * 64 + g * 4;
  const int cbase = bcol + wc * 64 + fr;
  if (MODE == 0) {
#pragma unroll
    for (int m = 0; m < 4; m++)
#pragma unroll
      for (int n = 0; n < 4; n++) {
        const int col = cbase + n * 16;
#pragma unroll
        for (int r = 0; r < 4; r++)
          ((float*)Cout)[(size_t)(rbase + m * 16 + r) * N + col] = acc[m][n][r];
      }
  } else if (bcol < 2 * EMB) {
    const float qscale = (bcol < EMB) ? SCL : 1.0f;
#pragma unroll
    for (int m = 0; m < 4; m++)
#pragma unroll
      for (int n = 0; n < 4; n++) {
        const int col = cbase + n * 16;
#pragma unroll
        for (int r = 0; r < 4; r++)
          ((__bf16*)Cout)[(size_t)(rbase + m * 16 + r) * N + col] = (__bf16)(acc[m][n][r] * qscale);
      }
  } else {
#pragma unroll
    for (int m = 0; m < 4; m++) {
      const int row0 = rbase + m * 16;
      const int b = row0 >> 11, t0 = row0 & 2047;
#pragma unroll
      for (int n = 0; n < 4; n++) {
        const int vcol = cbase + n * 16 - 2 * EMB;
        const int bh = b * HEADS + (vcol >> 6);
        const int d  = vcol & 63;
        u16x4 pk;
#pragma unroll
        for (int r = 0; r < 4; r++) {
          const __bf16 h = (__bf16)acc[m][n][r];
          pk[r] = *(const unsigned short*)&h;
        }
        *(u16x4*)(vt + ((size_t)bh * HD + d) * TT + t0) = pk;
      }
    }
  }
}

// ---------------------------------------------------------------------------
// Causal flash attention v20 (R21 winner, FROZEN): swapped QK^T, VALU-pipe
// softmax (permlane swaps + cvt_pk), ones-MFMA row-sum on the B-side,
// 3-deep K/V buffers, 3 blocks/CU, LPT, final-iter barrier skip.
// ---------------------------------------------------------------------------
__device__ __forceinline__ int psw(int row) {
  return (((row & 7) ^ ((row >> 3) & 7))) << 4;
}

__device__ __forceinline__ unsigned int pack_bf16(float a, float b) {
  unsigned int r;
  asm("v_cvt_pk_bf16_f32 %0, %1, %2" : "=v"(r) : "v"(a), "v"(b));
  return r;                                      // lo = bf16(a), hi = bf16(b)
}

__device__ __forceinline__ float opaque_f(float x) {
  float y;
  asm volatile("v_mov_b32 %0, %1" : "=v"(y) : "v"(x));
  return y;
}

__global__ __launch_bounds__(256, 3)
void attn_causal20(const __bf16* __restrict__ qkv, const __bf16* __restrict__ vt,
                   __bf16* __restrict__ yb) {
  __shared__ __align__(16) char Kbuf[3][8192];   // K[kv][d], chunk-swizzled
  __shared__ __align__(16) char Vbuf[3][8192];   // Vt[d][kv], chunk-swizzled

  const int tid = threadIdx.x;
  const int lane = tid & 63, w = tid >> 6;
  const int L = blockIdx.x;
  const int bh = L & 31;
  const int chunk = 31 - (L >> 5);               // LPT: longest first
  const int b = bh >> 4, h = bh & 15;
  const size_t rowbase = (size_t)b * TT;
  const int q0 = chunk * 64 + w * 16;
  const int fr = lane & 15, g = lane >> 4;
  const int ntiles = chunk + 1;

  bf16x8 qf[2];
#pragma unroll
  for (int kc = 0; kc < 2; kc++)
    qf[kc] = *(const bf16x8*)(qkv + (rowbase + q0 + fr) * QKVN + h * HD + kc * 32 + g * 8);

  bf16x8 ones;
#pragma unroll
  for (int j = 0; j < 8; j++) ones[j] = (__bf16)1.0f;

  f32x4 o[4];            // O^T frags: lane q=q0+fr holds d = n*16 + g*4 + r
  f32x4 lacc;            // ones-MFMA row-sum: all 4 regs = l_{q=fr}
  float ml = -1e30f;     // running max (scalar per lane)
#pragma unroll
  for (int n = 0; n < 4; n++)
#pragma unroll
    for (int r = 0; r < 4; r++) o[n][r] = 0.0f;
#pragma unroll
  for (int r = 0; r < 4; r++) lacc[r] = 0.0f;

  auto stageKV = [&](int kt, int buf) {
#pragma unroll
    for (int i = 0; i < 2; i++) {
      const int c = tid + i * 256;
      const int row = c >> 3;
      const int c16 = (c & 7) ^ (row & 7);
      gload_lds16(qkv + (rowbase + kt * 64 + row) * QKVN + EMB + h * HD + c16 * 8,
                  Kbuf[buf] + c * 16);
    }
#pragma unroll
    for (int i = 0; i < 2; i++) {
      const int c = tid + i * 256;
      const int row = c >> 3;
      const int c16 = (c & 7) ^ (row & 7);
      gload_lds16(vt + ((size_t)bh * HD + row) * TT + kt * 64 + c16 * 8,
                  Vbuf[buf] + c * 16);
    }
  };

  auto doQK = [&](int kt, f32x4 (&s)[4]) {
    const char* Kc = Kbuf[kt % 3];
    bf16x8 kf[4][2];
#pragma unroll
    for (int n = 0; n < 4; n++)
#pragma unroll
      for (int kc = 0; kc < 2; kc++) {
        const int row = n * 16 + fr;
        kf[n][kc] = *(const bf16x8*)(Kc + row * 128 + (((kc << 2) | g) ^ (row & 7)) * 16);
      }
    __builtin_amdgcn_s_setprio(1);
#pragma unroll
    for (int n = 0; n < 4; n++) {
#pragma unroll
      for (int r = 0; r < 4; r++) s[n][r] = 0.0f;
#pragma unroll
      for (int kc = 0; kc < 2; kc++)
        s[n] = __builtin_amdgcn_mfma_f32_16x16x32_bf16(kf[n][kc], qf[kc], s[n], 0, 0, 0);
    }
    __builtin_amdgcn_s_setprio(0);
  };

  auto doSM = [&](int kt, f32x4 (&s)[4], bf16x8 (&pb)[2]) {
    const int kv0 = kt * 64;
    if (kt == chunk) {                           // causal mask, diagonal tile
      const int qg = q0 + fr;
#pragma unroll
      for (int n = 0; n < 4; n++)
#pragma unroll
        for (int r = 0; r < 4; r++) {
          const int kg = kv0 + n * 16 + g * 4 + r;
          if (kg > qg) s[n][r] = -1e30f;
        }
    }
    float pm = s[0][0];
#pragma unroll
    for (int n = 0; n < 4; n++)
#pragma unroll
      for (int r = 0; r < 4; r++) pm = fmaxf(pm, s[n][r]);
    {
      float c16 = opaque_f(pm);
      asm("v_permlane16_swap_b32 %0, %1" : "+v"(pm), "+v"(c16));
      pm = fmaxf(pm, c16);
      float c32 = opaque_f(pm);
      asm("v_permlane32_swap_b32 %0, %1" : "+v"(pm), "+v"(c32));
      pm = fmaxf(pm, c32);
    }
    if (!__all(pm <= ml + THR)) {
      const float nm = fmaxf(ml, pm);
      const float f = __builtin_amdgcn_exp2f(ml - nm);
      ml = nm;
#pragma unroll
      for (int r = 0; r < 4; r++) lacc[r] *= f;
#pragma unroll
      for (int n = 0; n < 4; n++)
#pragma unroll
        for (int r = 0; r < 4; r++) o[n][r] *= f;
    }
    float p[4][4];
#pragma unroll
    for (int n = 0; n < 4; n++)
#pragma unroll
      for (int r = 0; r < 4; r++)
        p[n][r] = __builtin_amdgcn_exp2f(s[n][r] - ml);
    unsigned int pk[4][2];
#pragma unroll
    for (int n = 0; n < 4; n++)
#pragma unroll
      for (int w2 = 0; w2 < 2; w2++)
        pk[n][w2] = pack_bf16(p[n][2 * w2], p[n][2 * w2 + 1]);
#pragma unroll
    for (int kc = 0; kc < 2; kc++) {
      unsigned int a0 = pk[2 * kc][0], b0 = pk[2 * kc + 1][0];
      asm("v_permlane32_swap_b32 %0, %1" : "+v"(a0), "+v"(b0));
      asm("v_permlane16_swap_b32 %0, %1" : "+v"(a0), "+v"(b0));
      unsigned int a1 = pk[2 * kc][1], b1 = pk[2 * kc + 1][1];
      asm("v_permlane32_swap_b32 %0, %1" : "+v"(a1), "+v"(b1));
      asm("v_permlane16_swap_b32 %0, %1" : "+v"(a1), "+v"(b1));
      u32x4 bw;
      bw[0] = a0; bw[1] = a1; bw[2] = b0; bw[3] = b1;
      pb[kc] = *(bf16x8*)&bw;
    }
  };

  auto doPV = [&](int kt, bf16x8 (&pb)[2]) {
    const char* Vc = Vbuf[kt % 3];
    bf16x8 vb[4][2];
#pragma unroll
    for (int n = 0; n < 4; n++)
#pragma unroll
      for (int kc = 0; kc < 2; kc++) {
        const int row = n * 16 + fr;
        vb[n][kc] = *(const bf16x8*)(Vc + row * 128 + (((kc << 2) | g) ^ (row & 7)) * 16);
      }
    __builtin_amdgcn_s_setprio(1);
#pragma unroll
    for (int kc = 0; kc < 2; kc++) {
      lacc = __builtin_amdgcn_mfma_f32_16x16x32_bf16(ones, pb[kc], lacc, 0, 0, 0);
#pragma unroll
      for (int n = 0; n < 4; n++)
        o[n] = __builtin_amdgcn_mfma_f32_16x16x32_bf16(vb[n][kc], pb[kc], o[n], 0, 0, 0);
    }
    __builtin_amdgcn_s_setprio(0);
  };

  // ---- prologue: stage tiles 0,1; drain; tile-0 QK+SM ----
  stageKV(0, 0);
  if (ntiles > 1) stageKV(1, 1);
  asm volatile("s_waitcnt vmcnt(0)" ::: "memory");
  __builtin_amdgcn_s_barrier();

  bf16x8 pb[2];
  {
    f32x4 s0[4];
    doQK(0, s0);
    doSM(0, s0, pb);
  }

  for (int t = 0; t < ntiles; t++) {
    if (t + 2 < ntiles) stageKV(t + 2, (t + 2) % 3);

    const bool nxt = (t + 1 < ntiles);
    f32x4 s[4];
    if (nxt) doQK(t + 1, s);          // overlaps PV(t)
    doPV(t, pb);                      // consumes pb(t)
    if (nxt) doSM(t + 1, s, pb);      // rescale o AFTER PV(t); makes pb(t+1)

    if (nxt) {                        // final iteration: no drain, no barrier
      asm volatile("s_waitcnt vmcnt(0)" ::: "memory");
      __builtin_amdgcn_s_barrier();
    }
  }

  // ---- epilogue: O^T -> [q][d] via per-wave LDS region (Kbuf dead) ----
  {
    char* Tw = (char*)Kbuf + w * 2048;           // [16 q][64 d] bf16, psw-swizzled
    const float inv = __builtin_amdgcn_rcpf(lacc[0]);
#pragma unroll
    for (int n = 0; n < 4; n++)
#pragma unroll
      for (int r = 0; r < 4; r++) {
        const int d = n * 16 + g * 4 + r;
        *(__bf16*)(Tw + fr * 128 + ((d * 2) ^ psw(fr))) = (__bf16)(o[n][r] * inv);
      }
#pragma unroll
    for (int i = 0; i < 2; i++) {
      const int c = lane + i * 64;               // 128 16B-chunks
      const int row = c >> 3, pos = c & 7;
      const bf16x8 v = *(const bf16x8*)(Tw + row * 128 + ((pos * 16) ^ psw(row)));
      *(bf16x8*)(yb + (rowbase + q0 + row) * EMB + h * HD + pos * 8) = v;
    }
  }
}

extern "C" void kernel_launch(void* const* d_in, const int* in_sizes, int n_in,
                              void* d_out, int out_size, void* d_ws, size_t ws_size,
                              hipStream_t stream) {
  const float* x     = (const float*)d_in[0];
  const float* w_qkv = (const float*)d_in[1];
  const float* w_out = (const float*)d_in[2];
  float* out = (float*)d_out;

  char* ws = (char*)d_ws;
  __bf16* xb    = (__bf16*)(ws);                 // dead after gemm1 -> reused as yb
  __bf16* wqkvb = (__bf16*)(ws + (8ull  << 20));
  __bf16* wob   = (__bf16*)(ws + (14ull << 20));
  __bf16* qkvb  = (__bf16*)(ws + (16ull << 20));
  __bf16* vtb   = (__bf16*)(ws + (40ull << 20));
  __bf16* yb    = xb;

  cvt_all<<<4096, 256, 0, stream>>>(x, w_qkv, w_out, xb, wqkvb, wob);
  gemm_bt<1><<<dim3(QKVN / 128, NROWS / 128), 256, 0, stream>>>(xb, wqkvb, qkvb, vtb, NROWS, QKVN, EMB);
  attn_causal20<<<1024, 256, 0, stream>>>(qkvb, vtb, yb);
  gemm_bt<0><<<dim3(EMB / 128, NROWS / 128), 256, 0, stream>>>(yb, wob, out, nullptr, NROWS, EMB, EMB);
}